// Round 15
// baseline (116.168 us; speedup 1.0000x reference)
//
#include <hip/hip_runtime.h>
#include <hip/hip_bf16.h>
#include <math.h>

#define B_ 2
#define L_ 2048
#define D_ 1024
#define H_ 16
#define DH 64
#define ML (B_*L_)      // 4096
#define QKV_N 3072

typedef __attribute__((ext_vector_type(8)))  short bf16x8;
typedef __attribute__((ext_vector_type(4)))  float f32x4;
typedef __attribute__((ext_vector_type(16))) float f32x16;
typedef unsigned short u16;

__device__ __forceinline__ u16 f2bf(float f) {
    union { float f; unsigned u; } v; v.f = f;
    unsigned r = (v.u + 0x7FFFu + ((v.u >> 16) & 1u)) >> 16;
    return (u16)r;
}

__device__ __forceinline__ float bf2f(short s) {
    union { unsigned u; float f; } v;
    v.u = ((unsigned)(unsigned short)s) << 16;
    return v.f;
}

__device__ __forceinline__ float fexp2(float x) {
    float r; asm("v_exp_f32 %0, %1" : "=v"(r) : "v"(x)); return r;
}

// async global->LDS, 16B per lane. HW semantics: LDS dest = readfirstlane(ptr)
// + lane*16 -> ONLY use with full waves whose lane-0 pointer is the base.
__device__ __forceinline__ void async16(void* lds, const void* g) {
    __builtin_amdgcn_global_load_lds(
        (__attribute__((address_space(1))) unsigned int*)g,
        (__attribute__((address_space(3))) unsigned int*)lds,
        16, 0, 0);
}

// ---------------------------------------------------------------------------
// prep_kernel: pure casts (memory-bound).
//   blocks 0..4095    : Wq|Wk|Wv|Wo -> Wcat bf16 [4096][1024]
//   blocks 4096..8191 : x -> xb bf16 [4096][1024]
//   blocks 8192..8223 : [Ww;We] -> WG2 bf16 rows 0..31 (gate B-tile)
// ---------------------------------------------------------------------------
__global__ __launch_bounds__(256)
void prep_kernel(const float* __restrict__ x,
                 const float* __restrict__ Wq, const float* __restrict__ Wk,
                 const float* __restrict__ Wv, const float* __restrict__ Wo,
                 const float* __restrict__ Ww, const float* __restrict__ We,
                 u16* __restrict__ Wcat, u16* __restrict__ xb,
                 u16* __restrict__ WG2) {
    int blk = blockIdx.x, t = threadIdx.x;
    if (blk < 4096) {
        int i = (blk * 256 + t) * 4;
        int sel = i >> 20;
        const float* s = sel == 0 ? Wq : sel == 1 ? Wk : sel == 2 ? Wv : Wo;
        float4 v = *(const float4*)(s + (i & 1048575));
        ushort4 o;
        o.x = f2bf(v.x); o.y = f2bf(v.y); o.z = f2bf(v.z); o.w = f2bf(v.w);
        *(ushort4*)(Wcat + i) = o;
    } else if (blk < 8192) {
        int i = ((blk - 4096) * 256 + t) * 4;
        float4 v = *(const float4*)(x + i);
        ushort4 o;
        o.x = f2bf(v.x); o.y = f2bf(v.y); o.z = f2bf(v.z); o.w = f2bf(v.w);
        *(ushort4*)(xb + i) = o;
    } else {
        int i = ((blk - 8192) * 256 + t) * 4;    // 0..32767
        const float* s = (i < 16384) ? (Ww + i) : (We + i - 16384);
        float4 v = *(const float4*)s;
        ushort4 o;
        o.x = f2bf(v.x); o.y = f2bf(v.y); o.z = f2bf(v.z); o.w = f2bf(v.w);
        *(ushort4*)(WG2 + i) = o;
    }
}

// ---------------------------------------------------------------------------
// Inclusive scan per (b,h): CC = cumsum(GLOG); CJW = CC - LWG   (log2 domain)
// ---------------------------------------------------------------------------
__global__ __launch_bounds__(64)
void scan_kernel(const float* __restrict__ GLOG, const float* __restrict__ LWG,
                 float* __restrict__ CC, float* __restrict__ CJW) {
    int bh = blockIdx.x;
    int lane = threadIdx.x;
    const float* src = GLOG + (size_t)bh * L_;
    const float* lw  = LWG  + (size_t)bh * L_;
    float* dst  = CC  + (size_t)bh * L_;
    float* dstw = CJW + (size_t)bh * L_;
    float running = 0.f;
    for (int base = 0; base < L_; base += 64) {
        float v = src[base + lane];
#pragma unroll
        for (int off = 1; off < 64; off <<= 1) {
            float u = __shfl_up(v, off, 64);
            if (lane >= off) v += u;
        }
        float c = running + v;
        dst[base + lane]  = c;
        dstw[base + lane] = c - lw[base + lane];
        running += __shfl(v, 63, 64);
    }
}

// ---------------------------------------------------------------------------
// QKV+gates GEMM: BM=256 x BN=128 x BK=64, 8 waves (4M x 2N), 2-phase dbuf,
// XOR-swizzled LDS (T2/rule21). 2.7x arithmetic intensity of the 128^2 tile
// (48KB staged / 4.2 MFLOP per K-step) -> attacks the L3-staging-BW bound.
// nt<8  -> phi+bf16 to QK (Q cols); 8<=nt<16 -> phi+bf16 to QK (K) + Ktb^T;
// 16<=nt<24 -> V -> Vtb^T; nt==24 -> gate tile (B=WG2) -> LWG/GLOG (log2).
// ---------------------------------------------------------------------------
__global__ __launch_bounds__(512, 1)
void gemm_qkv(const u16* __restrict__ A, const u16* __restrict__ Bw,
              u16* __restrict__ QKo, u16* __restrict__ Ktb,
              u16* __restrict__ Vtb, const u16* __restrict__ WG2,
              const float* __restrict__ bw, const float* __restrict__ be,
              float* __restrict__ GLOG, float* __restrict__ LWG,
              int MT, int K) {
    __shared__ u16 As[2][16384];   // [256 row][64 k]  32KB each
    __shared__ u16 Bs[2][8192];    // [128 row][64 k]  16KB each
    int t = threadIdx.x;
    int id = (int)blockIdx.x;
    int lane = t & 63;
    int w = t >> 6, wm = w >> 1, wn = w & 1;    // 4M x 2N wave grid
    int l15 = lane & 15, l4 = lane >> 4;
    int nt = id / MT;
    int m0 = (id % MT) * 256, n0 = nt * 128;
    bool gate = (nt == 24);
    const u16* Bbase = gate ? WG2 : (Bw + (size_t)n0 * K);

    f32x4 zz = {0.f, 0.f, 0.f, 0.f};
    f32x4 acc[4][4];
#pragma unroll
    for (int m = 0; m < 4; m++)
#pragma unroll
        for (int n = 0; n < 4; n++) acc[m][n] = zz;

    auto STAGE = [&](int buf, int k0) {
#pragma unroll
        for (int i = 0; i < 4; i++) {           // A: 2048 chunks
            int c = i * 512 + t;
            int row = c >> 3;
            int ch = (c & 7) ^ (row & 7);
            async16(&As[buf][c * 8], A + (size_t)(m0 + row) * K + k0 + ch * 8);
        }
#pragma unroll
        for (int i = 0; i < 2; i++) {           // B: 1024 chunks
            int c = i * 512 + t;
            int row = c >> 3;
            int ch = (c & 7) ^ (row & 7);
            async16(&Bs[buf][c * 8], Bbase + (size_t)row * K + k0 + ch * 8);
        }
    };

    STAGE(0, 0);
    __syncthreads();

    int KT = K >> 6, cur = 0;
    for (int kt = 0; kt < KT; kt++) {
        if (kt + 1 < KT) STAGE(cur ^ 1, (kt + 1) << 6);

        bf16x8 af[4][2], bfr[4][2];
#pragma unroll
        for (int ks = 0; ks < 2; ks++) {
#pragma unroll
            for (int m = 0; m < 4; m++) {
                int row = wm * 64 + m * 16 + l15;          // 0..255
                int ch = (l4 + 4 * ks) ^ (row & 7);
                af[m][ks] = *(const bf16x8*)&As[cur][row * 64 + ch * 8];
            }
#pragma unroll
            for (int n = 0; n < 4; n++) {
                int row = wn * 64 + n * 16 + l15;          // 0..127
                int ch = (l4 + 4 * ks) ^ (row & 7);
                bfr[n][ks] = *(const bf16x8*)&Bs[cur][row * 64 + ch * 8];
            }
        }
#pragma unroll
        for (int m = 0; m < 4; m++)
#pragma unroll
            for (int n = 0; n < 4; n++) {
                acc[m][n] = __builtin_amdgcn_mfma_f32_16x16x32_bf16(af[m][0], bfr[n][0], acc[m][n], 0, 0, 0);
                acc[m][n] = __builtin_amdgcn_mfma_f32_16x16x32_bf16(af[m][1], bfr[n][1], acc[m][n], 0, 0, 0);
            }

        __syncthreads();
        cur ^= 1;
    }

    if (gate) {
        // gate epilogue: only cols 0..31 of this n-tile are live
#pragma unroll
        for (int m = 0; m < 4; m++)
#pragma unroll
            for (int n = 0; n < 4; n++) {
                int g = wn * 64 + n * 16 + l15;
                if (g < 32) {
                    int h = g & 15;
                    int rowb = m0 + wm * 64 + m * 16 + l4 * 4;
#pragma unroll
                    for (int r = 0; r < 4; r++) {
                        int row = rowb + r;
                        size_t idx = ((size_t)((row >> 11) * 16 + h)) * 2048 + (row & 2047);
                        float val = acc[m][n][r];
                        if (g < 16) {
                            float wgv = 1.f / (1.f + __expf(-(val + bw[h])));
                            LWG[idx] = __log2f(wgv);
                        } else {
                            float egv = 1.f / (1.f + __expf(-(val + be[h])));
                            GLOG[idx] = __log2f((1.f - egv) * 0.95f + 1e-8f);
                        }
                    }
                }
            }
        return;
    }

#pragma unroll
    for (int m = 0; m < 4; m++)
#pragma unroll
        for (int n = 0; n < 4; n++) {
            int colb = n0 + wn * 64 + n * 16 + l15;
            int rowb = m0 + wm * 64 + m * 16 + l4 * 4;
            if (colb < 1024) {
#pragma unroll
                for (int r = 0; r < 4; r++) {
                    float c = acc[m][n][r];
                    c = (c > 0.f) ? (c + 1.f) : __expf(c);
                    QKo[(size_t)(rowb + r) * 2048 + colb] = f2bf(c);
                }
            } else if (colb < 2048) {
                ushort4 o;
                u16 bv[4];
#pragma unroll
                for (int r = 0; r < 4; r++) {
                    float c = acc[m][n][r];
                    c = (c > 0.f) ? (c + 1.f) : __expf(c);
                    bv[r] = f2bf(c);
                    QKo[(size_t)(rowb + r) * 2048 + colb] = bv[r];
                }
                o.x = bv[0]; o.y = bv[1]; o.z = bv[2]; o.w = bv[3];
                int kcol = colb - 1024;
                int bb = rowb >> 11;
                *(ushort4*)&Ktb[((size_t)((bb * 16 + (kcol >> 6)) * 64 + (kcol & 63))) * 2048 + (rowb & 2047)] = o;
            } else {
                int vcol = colb - 2048;
                int bb = rowb >> 11;
                ushort4 o;
                o.x = f2bf(acc[m][n][0]); o.y = f2bf(acc[m][n][1]);
                o.z = f2bf(acc[m][n][2]); o.w = f2bf(acc[m][n][3]);
                *(ushort4*)&Vtb[((size_t)((bb * 16 + (vcol >> 6)) * 64 + (vcol & 63))) * 2048 + (rowb & 2047)] = o;
            }
        }
}

// ---------------------------------------------------------------------------
// Wo GEMM (verified 128^2 structure): C[M,N] = A[M,K] @ W[N,K]^T, f32 out.
// ---------------------------------------------------------------------------
__global__ __launch_bounds__(256)
void gemm_wo(const u16* __restrict__ A, const u16* __restrict__ Bw,
             float* __restrict__ Cout, int MT, int N, int K) {
    __shared__ u16 As[2][8192];
    __shared__ u16 Bs[2][8192];
    int t = threadIdx.x;
    int id = (int)blockIdx.x;
    int lane = t & 63;
    int w = t >> 6, wm = w >> 1, wn = w & 1;
    int l15 = lane & 15, l4 = lane >> 4;
    int m0 = (id % MT) * 128, n0 = (id / MT) * 128;

    f32x4 zz = {0.f, 0.f, 0.f, 0.f};
    f32x4 acc[4][4];
#pragma unroll
    for (int m = 0; m < 4; m++)
#pragma unroll
        for (int n = 0; n < 4; n++) acc[m][n] = zz;

    auto STAGE = [&](int buf, int k0) {
#pragma unroll
        for (int i = 0; i < 4; i++) {
            int c = i * 256 + t;
            int row = c >> 3;
            int ch = (c & 7) ^ (row & 7);
            async16(&As[buf][c * 8], A  + (size_t)(m0 + row) * K + k0 + ch * 8);
            async16(&Bs[buf][c * 8], Bw + (size_t)(n0 + row) * K + k0 + ch * 8);
        }
    };

    STAGE(0, 0);
    __syncthreads();

    int KT = K >> 6, cur = 0;
    for (int kt = 0; kt < KT; kt++) {
        if (kt + 1 < KT) STAGE(cur ^ 1, (kt + 1) << 6);

        bf16x8 af[4][2], bfr[4][2];
#pragma unroll
        for (int ks = 0; ks < 2; ks++) {
#pragma unroll
            for (int m = 0; m < 4; m++) {
                int row = wm * 64 + m * 16 + l15;
                int ch = (l4 + 4 * ks) ^ (row & 7);
                af[m][ks] = *(const bf16x8*)&As[cur][row * 64 + ch * 8];
            }
#pragma unroll
            for (int n = 0; n < 4; n++) {
                int row = wn * 64 + n * 16 + l15;
                int ch = (l4 + 4 * ks) ^ (row & 7);
                bfr[n][ks] = *(const bf16x8*)&Bs[cur][row * 64 + ch * 8];
            }
        }
#pragma unroll
        for (int m = 0; m < 4; m++)
#pragma unroll
            for (int n = 0; n < 4; n++) {
                acc[m][n] = __builtin_amdgcn_mfma_f32_16x16x32_bf16(af[m][0], bfr[n][0], acc[m][n], 0, 0, 0);
                acc[m][n] = __builtin_amdgcn_mfma_f32_16x16x32_bf16(af[m][1], bfr[n][1], acc[m][n], 0, 0, 0);
            }

        __syncthreads();
        cur ^= 1;
    }

#pragma unroll
    for (int m = 0; m < 4; m++)
#pragma unroll
        for (int n = 0; n < 4; n++) {
            int colb = n0 + wn * 64 + n * 16 + l15;
            int rowb = m0 + wm * 64 + m * 16 + l4 * 4;
#pragma unroll
            for (int r = 0; r < 4; r++)
                Cout[(size_t)(rowb + r) * N + colb] = acc[m][n][r];
        }
}

// ---------------------------------------------------------------------------
// Phase A: per-chunk state delta. Block = (chunk c, bh), 128 thr = 2 waves.
// dS[v][k] = sum_{j in chunk} Vt[v][j] * Kt[k][j] * 2^(cref - a_j)  (bf16 out)
// dZ[k]    = sum_{j in chunk} Kt[k][j] * 2^(cref - a_j)             (f32 out)
// ---------------------------------------------------------------------------
__global__ __launch_bounds__(128)
void state_delta(const u16* __restrict__ Ktb, const u16* __restrict__ Vtb,
                 const float* __restrict__ CCg, const float* __restrict__ CJWg,
                 u16* __restrict__ dSg, float* __restrict__ dZg) {
    __shared__ u16 Kts[4096], Vts[4096];
    __shared__ float cjl[64];
    int c = blockIdx.x, bh = blockIdx.y;
    int j0 = c * 64;
    int t = threadIdx.x, w = t >> 6, lane = t & 63, l31 = lane & 31, hi = lane >> 5;
    const u16* ktg = Ktb + (size_t)(bh * 64) * 2048 + j0;
    const u16* vtg = Vtb + (size_t)(bh * 64) * 2048 + j0;
#pragma unroll
    for (int rnd = 0; rnd < 4; rnd++) {
        int cc_ = rnd * 128 + t; int row = cc_ >> 3; int ch = (cc_ & 7) ^ (row & 7);
        async16(&Kts[cc_ * 8], ktg + (size_t)row * 2048 + ch * 8);
        async16(&Vts[cc_ * 8], vtg + (size_t)row * 2048 + ch * 8);
    }
    if (t < 64) cjl[t] = CJWg[(size_t)bh * L_ + j0 + t];   // plain store (rule 21!)
    float cref = CCg[(size_t)bh * L_ + j0 + 63];
    __syncthreads();

    f32x16 zz16;
#pragma unroll
    for (int r = 0; r < 16; r++) zz16[r] = 0.f;
    int swz = l31 & 7;
    int vq = w;
    u16* base = dSg + (size_t)(bh * 32 + c) * 4096;

#pragma unroll
    for (int kq = 0; kq < 2; kq++) {
        f32x16 acc = zz16;
        float zs = 0.f;
#pragma unroll
        for (int ks = 0; ks < 4; ks++) {
            int ch = (ks * 2 + hi) ^ swz;
            bf16x8 kt = *(const bf16x8*)&Kts[(kq * 32 + l31) * 64 + ch * 8];
            bf16x8 vt = *(const bf16x8*)&Vts[(vq * 32 + l31) * 64 + ch * 8];
            union { unsigned u[4]; bf16x8 v; } kw;
#pragma unroll
            for (int e2 = 0; e2 < 4; e2++) {
                int jb = ks * 16 + hi * 8 + e2 * 2;
                float f0 = bf2f(kt[e2 * 2 + 0]) * fexp2(cref - cjl[jb]);
                float f1 = bf2f(kt[e2 * 2 + 1]) * fexp2(cref - cjl[jb + 1]);
                zs += f0 + f1;
                asm("v_cvt_pk_bf16_f32 %0, %1, %2" : "=v"(kw.u[e2]) : "v"(f0), "v"(f1));
            }
            acc = __builtin_amdgcn_mfma_f32_32x32x16_bf16(vt, kw.v, acc, 0, 0, 0);
        }
#pragma unroll
        for (int r = 0; r < 16; r++) {
            int v = vq * 32 + (r & 3) + 8 * (r >> 2) + 4 * hi;
            base[v * 64 + kq * 32 + l31] = f2bf(acc[r]);
        }
        if (w == 0) {
            zs += __shfl_xor(zs, 32, 64);
            if (hi == 0)
                dZg[(size_t)(bh * 32 + c) * 64 + kq * 32 + l31] = zs;
        }
    }
}

// ---------------------------------------------------------------------------
// Phase B: per-element scan over 32 chunks. Grid (32 bh, 9): y<8 = state
// slices (each thread 2 elements), y==8 = z (t<64). fp32 accum, bf16 S out.
// ---------------------------------------------------------------------------
__global__ __launch_bounds__(256)
void state_scan(const u16* __restrict__ dSg, const float* __restrict__ dZg,
                const float* __restrict__ CCg,
                u16* __restrict__ Sg, float* __restrict__ Zg) {
    __shared__ float lam[32];
    int bh = blockIdx.x, slice = blockIdx.y;
    int t = threadIdx.x;
    if (t < 32) {
        float cr = CCg[(size_t)bh * L_ + t * 64 + 63];
        float cp = t ? CCg[(size_t)bh * L_ + t * 64 - 1] : 0.f;
        lam[t] = t ? fexp2(cr - cp) : 0.f;
    }
    __syncthreads();
    if (slice < 8) {
        int eidx = slice * 512 + t * 2;
        float s0 = 0.f, s1 = 0.f;
#pragma unroll 8
        for (int c = 0; c < 32; c++) {
            unsigned d = *(const unsigned*)&dSg[(size_t)(bh * 32 + c) * 4096 + eidx];
            float l = lam[c];
            s0 = l * s0 + bf2f((short)(d & 0xffff));
            s1 = l * s1 + bf2f((short)(d >> 16));
            unsigned o;
            asm("v_cvt_pk_bf16_f32 %0, %1, %2" : "=v"(o) : "v"(s0), "v"(s1));
            *(unsigned*)&Sg[(size_t)(bh * 32 + c) * 4096 + eidx] = o;
        }
    } else if (t < 64) {
        float z = 0.f;
#pragma unroll 8
        for (int c = 0; c < 32; c++) {
            z = lam[c] * z + dZg[(size_t)(bh * 32 + c) * 64 + t];
            Zg[(size_t)(bh * 32 + c) * 64 + t] = z;
        }
    }
}

// ---------------------------------------------------------------------------
// Phase C: output. Block = (chunk c, bh), 128 thr = 2 waves x 32 i-rows.
// out_i = [ intra (triangular QK^T*decay @ V) + 2^(c_i - cref_{c-1}) Q_i@S_{c-1} ]
//         / [ intra_den + 2^(c_i - cref_{c-1}) Q_i.z_{c-1} + eps ]
// ---------------------------------------------------------------------------
__global__ __launch_bounds__(128)
void attn_out(const u16* __restrict__ QK, const u16* __restrict__ Vtb,
              const u16* __restrict__ Sg, const float* __restrict__ Zg,
              const float* __restrict__ CCg, const float* __restrict__ CJWg,
              u16* __restrict__ AOb) {
    __shared__ u16 Qs[4096], Ks[4096], Vts[4096], Ss[4096];
    __shared__ float ccl[64], cjl[64], zbl[64];
    int c = blockIdx.x, bh = blockIdx.y;
    int b = bh >> 4, h = bh & 15;
    int j0 = c * 64;
    int t = threadIdx.x, w = t >> 6, lane = t & 63, l31 = lane & 31, hi = lane >> 5;
    int w32 = w * 32;

    const u16* qkg = QK + (size_t)(b * L_ + j0) * 2048 + h * 64;
    const u16* vtg = Vtb + (size_t)(bh * 64) * 2048 + j0;
#pragma unroll
    for (int rnd = 0; rnd < 4; rnd++) {
        int cc_ = rnd * 128 + t; int row = cc_ >> 3; int ch = (cc_ & 7) ^ (row & 7);
        async16(&Qs[cc_ * 8],  qkg + (size_t)row * 2048 + ch * 8);
        async16(&Ks[cc_ * 8],  qkg + (size_t)row * 2048 + 1024 + ch * 8);
        async16(&Vts[cc_ * 8], vtg + (size_t)row * 2048 + ch * 8);
    }
    if (c) {
        const u16* sg = Sg + (size_t)(bh * 32 + c - 1) * 4096;
#pragma unroll
        for (int rnd = 0; rnd < 4; rnd++) {
            int cc_ = rnd * 128 + t; int row = cc_ >> 3; int ch = (cc_ & 7) ^ (row & 7);
            async16(&Ss[cc_ * 8], sg + row * 64 + ch * 8);
        }
        if (t < 64) zbl[t] = Zg[(size_t)(bh * 32 + c - 1) * 64 + t];  // plain store
    }
    // plain per-lane stores for the small fp32 arrays (rule 21: async16 with
    // a non-lane0 base writes base+lane*16, NOT per-lane scatter)
    if (t < 64) {
        ccl[t] = CCg[(size_t)bh * L_ + j0 + t];
        cjl[t] = CJWg[(size_t)bh * L_ + j0 + t];
    }
    float cpv = c ? CCg[(size_t)bh * L_ + j0 - 1] : 0.f;
    __syncthreads();

    f32x16 zz16;
#pragma unroll
    for (int r = 0; r < 16; r++) zz16[r] = 0.f;
    int swz = l31 & 7;

    // Q fragments (A- and B-operand layouts are identical: lane&31 = row)
    bf16x8 qb[4];
#pragma unroll
    for (int ks = 0; ks < 4; ks++) {
        int ch = (ks * 2 + hi) ^ swz;
        qb[ks] = *(const bf16x8*)&Qs[(w32 + l31) * 64 + ch * 8];
    }
    float ci = ccl[w32 + l31];

    // ---- intra QK^T (swapped): st = S^T frag, i = l31 col ----
    f32x16 st[2];
    st[0] = zz16; st[1] = zz16;
    __builtin_amdgcn_s_setprio(1);
#pragma unroll
    for (int ks = 0; ks < 4; ks++) {
        int ch = (ks * 2 + hi) ^ swz;
        bf16x8 k0 = *(const bf16x8*)&Ks[l31 * 64 + ch * 8];
        bf16x8 k1 = *(const bf16x8*)&Ks[(32 + l31) * 64 + ch * 8];
        st[0] = __builtin_amdgcn_mfma_f32_32x32x16_bf16(k0, qb[ks], st[0], 0, 0, 0);
        st[1] = __builtin_amdgcn_mfma_f32_32x32x16_bf16(k1, qb[ks], st[1], 0, 0, 0);
    }
    __builtin_amdgcn_s_setprio(0);

    // ---- P build (triangular), pack bf16 ----
    unsigned pk[2][4][2];
    float dloc = 0.f;
    int lim = w32 + l31;
#pragma unroll
    for (int n = 0; n < 2; n++) {
#pragma unroll
        for (int rq = 0; rq < 4; rq++) {
            float4 cj4 = *(const float4*)&cjl[n * 32 + rq * 8 + hi * 4];
            float e0 = st[n][rq * 4 + 0] * fexp2(ci - cj4.x);
            float e1 = st[n][rq * 4 + 1] * fexp2(ci - cj4.y);
            float e2 = st[n][rq * 4 + 2] * fexp2(ci - cj4.z);
            float e3 = st[n][rq * 4 + 3] * fexp2(ci - cj4.w);
            int jb = n * 32 + rq * 8 + hi * 4;
            e0 = (jb + 0 <= lim) ? e0 : 0.f;
            e1 = (jb + 1 <= lim) ? e1 : 0.f;
            e2 = (jb + 2 <= lim) ? e2 : 0.f;
            e3 = (jb + 3 <= lim) ? e3 : 0.f;
            dloc += (e0 + e1) + (e2 + e3);
            asm("v_cvt_pk_bf16_f32 %0, %1, %2" : "=v"(pk[n][rq][0]) : "v"(e0), "v"(e1));
            asm("v_cvt_pk_bf16_f32 %0, %1, %2" : "=v"(pk[n][rq][1]) : "v"(e2), "v"(e3));
        }
    }

    // ---- PV ----
    f32x16 acc0 = zz16, acc1 = zz16;
    __builtin_amdgcn_s_setprio(1);
#pragma unroll
    for (int wi = 0; wi < 4; wi++) {
        int n = wi >> 1, qA = 2 * (wi & 1), qB = qA + 1;
        unsigned a0 = pk[n][qA][0], b0 = pk[n][qB][0];
        unsigned a1 = pk[n][qA][1], b1 = pk[n][qB][1];
        asm volatile("v_permlane32_swap_b32 %0, %1" : "+v"(a0), "+v"(b0));
        asm volatile("v_permlane32_swap_b32 %0, %1" : "+v"(a1), "+v"(b1));
        union { unsigned u[4]; bf16x8 v; } aw;
        aw.u[0] = a0; aw.u[1] = a1; aw.u[2] = b0; aw.u[3] = b1;
        int jc = (wi * 2 + hi) ^ swz;
        bf16x8 v0 = *(const bf16x8*)&Vts[l31 * 64 + jc * 8];
        bf16x8 v1 = *(const bf16x8*)&Vts[(32 + l31) * 64 + jc * 8];
        acc0 = __builtin_amdgcn_mfma_f32_32x32x16_bf16(aw.v, v0, acc0, 0, 0, 0);
        acc1 = __builtin_amdgcn_mfma_f32_32x32x16_bf16(aw.v, v1, acc1, 0, 0, 0);
    }
    __builtin_amdgcn_s_setprio(0);

    // ---- inter: Q @ S_{c-1}, Q . z_{c-1} ----
    if (c) {
        f32x16 oi0 = zz16, oi1 = zz16;
        __builtin_amdgcn_s_setprio(1);
#pragma unroll
        for (int ks = 0; ks < 4; ks++) {
            int ch = (ks * 2 + hi) ^ swz;
            bf16x8 s0 = *(const bf16x8*)&Ss[l31 * 64 + ch * 8];
            bf16x8 s1 = *(const bf16x8*)&Ss[(32 + l31) * 64 + ch * 8];
            oi0 = __builtin_amdgcn_mfma_f32_32x32x16_bf16(qb[ks], s0, oi0, 0, 0, 0);
            oi1 = __builtin_amdgcn_mfma_f32_32x32x16_bf16(qb[ks], s1, oi1, 0, 0, 0);
        }
        __builtin_amdgcn_s_setprio(0);
#pragma unroll
        for (int r = 0; r < 16; r++) {
            int il = (r & 3) + 8 * (r >> 2) + 4 * hi;
            float sc = fexp2(ccl[w32 + il] - cpv);
            acc0[r] += sc * oi0[r];
            acc1[r] += sc * oi1[r];
        }
        float dq = 0.f;
#pragma unroll
        for (int ks = 0; ks < 4; ks++)
#pragma unroll
            for (int e = 0; e < 8; e++)
                dq += bf2f(qb[ks][e]) * zbl[ks * 16 + hi * 8 + e];
        dloc += fexp2(ci - cpv) * dq;
    }

    // ---- denominator broadcast + output ----
    float dl = dloc + __shfl_xor(dloc, 32, 64);
#pragma unroll
    for (int r = 0; r < 16; r++) {
        int il = (r & 3) + 8 * (r >> 2) + 4 * hi;
        float dv = __shfl(dl, il, 64);
        float inv = 1.f / (dv + 1e-6f);
        int ig = j0 + w32 + il;
        AOb[(size_t)(b * L_ + ig) * D_ + h * DH + l31]      = f2bf(acc0[r] * inv);
        AOb[(size_t)(b * L_ + ig) * D_ + h * DH + 32 + l31] = f2bf(acc1[r] * inv);
    }
}

// ---------------------------------------------------------------------------
extern "C" void kernel_launch(void* const* d_in, const int* in_sizes, int n_in,
                              void* d_out, int out_size, void* d_ws, size_t ws_size,
                              hipStream_t stream) {
    const float* x  = (const float*)d_in[0];
    const float* Wq = (const float*)d_in[1];
    const float* Wk = (const float*)d_in[2];
    const float* Wv = (const float*)d_in[3];
    const float* Wo = (const float*)d_in[4];
    const float* Ww = (const float*)d_in[5];
    const float* bw = (const float*)d_in[6];
    const float* We = (const float*)d_in[7];
    const float* be = (const float*)d_in[8];
    float* out = (float*)d_out;

    char* wsb = (char*)d_ws;
    u16* xb   = (u16*)(wsb);                        // 8MB (dead after QKV gemm)
    u16* Sg   = xb;                                 // 8MB, reuses xb region
    u16* Wcat = (u16*)(wsb + ((size_t)8  << 20));   // 8MB  [Wq;Wk;Wv;Wo] bf16
    u16* QK   = (u16*)(wsb + ((size_t)16 << 20));   // 16MB [4096][2048] Q|K phi'd
    u16* Vtb  = (u16*)(wsb + ((size_t)32 << 20));   // 8MB  [B*H*64][2048]
    u16* Ktb  = (u16*)(wsb + ((size_t)40 << 20));   // 8MB  [B*H*64][2048]
    u16* AOb  = (u16*)(wsb + ((size_t)48 << 20));   // 8MB  [4096][1024]
    u16* dSg  = AOb;                                // 8MB, consumed before AOb written
    float* GLOG = (float*)(wsb + ((size_t)56 << 20));
    float* LWG  = GLOG + 65536;
    float* CC   = LWG  + 65536;
    float* CJW  = CC   + 65536;
    float* dZg  = CJW  + 65536;   // 256KB
    float* Zg   = dZg  + 65536;   // 256KB
    u16*  WG2  = (u16*)(Zg + 65536);   // 256KB [128][1024] bf16 gate B-tile

    // 1) pure casts: weights, x, gate-weights
    prep_kernel<<<8224, 256, 0, stream>>>(
        x, Wq, Wk, Wv, Wo, Ww, We, Wcat, xb, WG2);

    // 2) fused QKV + gates projection, 256x128 tiles (16 m x 25 n)
    gemm_qkv<<<16 * 25, 512, 0, stream>>>(
        xb, Wcat, QK, Ktb, Vtb, WG2, bw, be, GLOG, LWG, 16, D_);

    // 3) log-decay scan
    scan_kernel<<<B_ * H_, 64, 0, stream>>>(GLOG, LWG, CC, CJW);

    // 4-6) chunked linear attention
    state_delta<<<dim3(32, B_ * H_), 128, 0, stream>>>(Ktb, Vtb, CC, CJW, dSg, dZg);
    state_scan<<<dim3(B_ * H_, 9), 256, 0, stream>>>(dSg, dZg, CC, Sg, Zg);
    attn_out<<<dim3(32, B_ * H_), 128, 0, stream>>>(QK, Vtb, Sg, Zg, CC, CJW, AOb);

    // 7) output projection (verified 128^2 kernel)
    gemm_wo<<<(ML / 128) * (D_ / 128), 256, 0, stream>>>(
        AOb, Wcat + (size_t)3072 * 1024, out, ML / 128, D_, D_);
}

// Round 16
// 112.141 us; speedup vs baseline: 1.0359x; 1.0359x over previous
//
#include <hip/hip_runtime.h>
#include <hip/hip_bf16.h>
#include <math.h>

#define B_ 2
#define L_ 2048
#define D_ 1024
#define H_ 16
#define DH 64
#define ML (B_*L_)      // 4096
#define QKV_N 3072

typedef __attribute__((ext_vector_type(8)))  short bf16x8;
typedef __attribute__((ext_vector_type(4)))  float f32x4;
typedef __attribute__((ext_vector_type(16))) float f32x16;
typedef unsigned short u16;

__device__ __forceinline__ u16 f2bf(float f) {
    union { float f; unsigned u; } v; v.f = f;
    unsigned r = (v.u + 0x7FFFu + ((v.u >> 16) & 1u)) >> 16;
    return (u16)r;
}

__device__ __forceinline__ float bf2f(short s) {
    union { unsigned u; float f; } v;
    v.u = ((unsigned)(unsigned short)s) << 16;
    return v.f;
}

__device__ __forceinline__ float fexp2(float x) {
    float r; asm("v_exp_f32 %0, %1" : "=v"(r) : "v"(x)); return r;
}

// async global->LDS, 16B per lane. HW semantics: LDS dest = readfirstlane(ptr)
// + lane*16 -> ONLY use with full waves whose lane-0 pointer is the base.
__device__ __forceinline__ void async16(void* lds, const void* g) {
    __builtin_amdgcn_global_load_lds(
        (__attribute__((address_space(1))) unsigned int*)g,
        (__attribute__((address_space(3))) unsigned int*)lds,
        16, 0, 0);
}

// 2D XCD-aware tile decode (MT must be 32 = 4 m-tiles per XCD x 8 XCDs).
// Each XCD owns m-tiles [4*xcd, 4*xcd+4) across ALL n-tiles, walked n-major:
// L2 working set = 4 A-panels (1MB, resident) + hot B-panel (512KB).
__device__ __forceinline__ void xcd_decode(int id, int& mt, int& nt) {
    int xcd = id & 7;
    int r = id >> 3;
    nt = r >> 2;
    mt = (xcd << 2) | (r & 3);
}

// ---------------------------------------------------------------------------
// prep_kernel: pure casts (memory-bound).
//   blocks 0..4095    : Wq|Wk|Wv|Wo -> Wcat bf16 [4096][1024]
//   blocks 4096..8191 : x -> xb bf16 [4096][1024]
//   blocks 8192..8223 : [Ww;We] -> WG2 bf16 rows 0..31 (gate B-tile)
// ---------------------------------------------------------------------------
__global__ __launch_bounds__(256)
void prep_kernel(const float* __restrict__ x,
                 const float* __restrict__ Wq, const float* __restrict__ Wk,
                 const float* __restrict__ Wv, const float* __restrict__ Wo,
                 const float* __restrict__ Ww, const float* __restrict__ We,
                 u16* __restrict__ Wcat, u16* __restrict__ xb,
                 u16* __restrict__ WG2) {
    int blk = blockIdx.x, t = threadIdx.x;
    if (blk < 4096) {
        int i = (blk * 256 + t) * 4;
        int sel = i >> 20;
        const float* s = sel == 0 ? Wq : sel == 1 ? Wk : sel == 2 ? Wv : Wo;
        float4 v = *(const float4*)(s + (i & 1048575));
        ushort4 o;
        o.x = f2bf(v.x); o.y = f2bf(v.y); o.z = f2bf(v.z); o.w = f2bf(v.w);
        *(ushort4*)(Wcat + i) = o;
    } else if (blk < 8192) {
        int i = ((blk - 4096) * 256 + t) * 4;
        float4 v = *(const float4*)(x + i);
        ushort4 o;
        o.x = f2bf(v.x); o.y = f2bf(v.y); o.z = f2bf(v.z); o.w = f2bf(v.w);
        *(ushort4*)(xb + i) = o;
    } else {
        int i = ((blk - 8192) * 256 + t) * 4;    // 0..32767
        const float* s = (i < 16384) ? (Ww + i) : (We + i - 16384);
        float4 v = *(const float4*)s;
        ushort4 o;
        o.x = f2bf(v.x); o.y = f2bf(v.y); o.z = f2bf(v.z); o.w = f2bf(v.w);
        *(ushort4*)(WG2 + i) = o;
    }
}

// ---------------------------------------------------------------------------
// Inclusive scan per (b,h): CC = cumsum(GLOG); CJW = CC - LWG   (log2 domain)
// ---------------------------------------------------------------------------
__global__ __launch_bounds__(64)
void scan_kernel(const float* __restrict__ GLOG, const float* __restrict__ LWG,
                 float* __restrict__ CC, float* __restrict__ CJW) {
    int bh = blockIdx.x;
    int lane = threadIdx.x;
    const float* src = GLOG + (size_t)bh * L_;
    const float* lw  = LWG  + (size_t)bh * L_;
    float* dst  = CC  + (size_t)bh * L_;
    float* dstw = CJW + (size_t)bh * L_;
    float running = 0.f;
    for (int base = 0; base < L_; base += 64) {
        float v = src[base + lane];
#pragma unroll
        for (int off = 1; off < 64; off <<= 1) {
            float u = __shfl_up(v, off, 64);
            if (lane >= off) v += u;
        }
        float c = running + v;
        dst[base + lane]  = c;
        dstw[base + lane] = c - lw[base + lane];
        running += __shfl(v, 63, 64);
    }
}

// ---------------------------------------------------------------------------
// bf16 MFMA GEMM: 128x128 tile, BK=64, 4 waves, 2-phase dbuf, XOR-swizzled
// LDS (T2/rule21), 2D XCD-aware tile map.
// mode 1: f32 row-major out (stride N).
// mode 2: QKV+gates: nt<8  -> phi+bf16 to QK (Q cols);
//         8<=nt<16 -> phi+bf16 to QK (K cols) + transposed to Ktb;
//         16<=nt<24 -> V transposed to Vtb; nt==24 -> gate tile (B=WG2).
// ---------------------------------------------------------------------------
__global__ __launch_bounds__(256)
void gemm_fused(const u16* __restrict__ A, const u16* __restrict__ Bw,
                void* __restrict__ Cout, u16* __restrict__ Ktb,
                u16* __restrict__ Vtb, const u16* __restrict__ WG2,
                const float* __restrict__ bw, const float* __restrict__ be,
                float* __restrict__ GLOG, float* __restrict__ LWG,
                int N, int K, int mode) {
    __shared__ u16 As[2][8192];   // [128 row][64 k]
    __shared__ u16 Bs[2][8192];
    int t = threadIdx.x;
    int lane = t & 63;
    int w = t >> 6, wm = w >> 1, wn = w & 1;
    int l15 = lane & 15, l4 = lane >> 4;
    int mt, nt;
    xcd_decode((int)blockIdx.x, mt, nt);
    int m0 = mt * 128, n0 = nt * 128;
    bool gate = (mode == 2) && (nt == 24);
    const u16* Bbase = gate ? WG2 : (Bw + (size_t)n0 * K);

    f32x4 zz = {0.f, 0.f, 0.f, 0.f};
    f32x4 acc[4][4];
#pragma unroll
    for (int m = 0; m < 4; m++)
#pragma unroll
        for (int n = 0; n < 4; n++) acc[m][n] = zz;

    auto STAGE = [&](int buf, int k0) {
#pragma unroll
        for (int i = 0; i < 4; i++) {
            int c = i * 256 + t;
            int row = c >> 3;
            int ch = (c & 7) ^ (row & 7);
            async16(&As[buf][c * 8], A     + (size_t)(m0 + row) * K + k0 + ch * 8);
            async16(&Bs[buf][c * 8], Bbase + (size_t)row * K + k0 + ch * 8);
        }
    };

    STAGE(0, 0);
    __syncthreads();

    int KT = K >> 6, cur = 0;
    for (int kt = 0; kt < KT; kt++) {
        if (kt + 1 < KT) STAGE(cur ^ 1, (kt + 1) << 6);

        bf16x8 af[4][2], bfr[4][2];
#pragma unroll
        for (int ks = 0; ks < 2; ks++) {
#pragma unroll
            for (int m = 0; m < 4; m++) {
                int row = wm * 64 + m * 16 + l15;
                int ch = (l4 + 4 * ks) ^ (row & 7);
                af[m][ks] = *(const bf16x8*)&As[cur][row * 64 + ch * 8];
            }
#pragma unroll
            for (int n = 0; n < 4; n++) {
                int row = wn * 64 + n * 16 + l15;
                int ch = (l4 + 4 * ks) ^ (row & 7);
                bfr[n][ks] = *(const bf16x8*)&Bs[cur][row * 64 + ch * 8];
            }
        }
#pragma unroll
        for (int m = 0; m < 4; m++)
#pragma unroll
            for (int n = 0; n < 4; n++) {
                acc[m][n] = __builtin_amdgcn_mfma_f32_16x16x32_bf16(af[m][0], bfr[n][0], acc[m][n], 0, 0, 0);
                acc[m][n] = __builtin_amdgcn_mfma_f32_16x16x32_bf16(af[m][1], bfr[n][1], acc[m][n], 0, 0, 0);
            }

        __syncthreads();
        cur ^= 1;
    }

    if (gate) {
        // gate epilogue: only cols 0..31 of this tile are live
#pragma unroll
        for (int m = 0; m < 4; m++)
#pragma unroll
            for (int n = 0; n < 4; n++) {
                int g = wn * 64 + n * 16 + l15;
                if (g < 32) {
                    int h = g & 15;
                    int rowb = m0 + wm * 64 + m * 16 + l4 * 4;
#pragma unroll
                    for (int r = 0; r < 4; r++) {
                        int row = rowb + r;
                        size_t idx = ((size_t)((row >> 11) * 16 + h)) * 2048 + (row & 2047);
                        float val = acc[m][n][r];
                        if (g < 16) {
                            float wgv = 1.f / (1.f + __expf(-(val + bw[h])));
                            LWG[idx] = __log2f(wgv);
                        } else {
                            float egv = 1.f / (1.f + __expf(-(val + be[h])));
                            GLOG[idx] = __log2f((1.f - egv) * 0.95f + 1e-8f);
                        }
                    }
                }
            }
        return;
    }

#pragma unroll
    for (int m = 0; m < 4; m++)
#pragma unroll
        for (int n = 0; n < 4; n++) {
            int colb = n0 + wn * 64 + n * 16 + l15;
            int rowb = m0 + wm * 64 + m * 16 + l4 * 4;
            if (mode == 1) {
#pragma unroll
                for (int r = 0; r < 4; r++)
                    ((float*)Cout)[(size_t)(rowb + r) * N + colb] = acc[m][n][r];
            } else {
                if (colb < 1024) {
#pragma unroll
                    for (int r = 0; r < 4; r++) {
                        float c = acc[m][n][r];
                        c = (c > 0.f) ? (c + 1.f) : __expf(c);
                        ((u16*)Cout)[(size_t)(rowb + r) * 2048 + colb] = f2bf(c);
                    }
                } else if (colb < 2048) {
                    ushort4 o;
                    u16 bv[4];
#pragma unroll
                    for (int r = 0; r < 4; r++) {
                        float c = acc[m][n][r];
                        c = (c > 0.f) ? (c + 1.f) : __expf(c);
                        bv[r] = f2bf(c);
                        ((u16*)Cout)[(size_t)(rowb + r) * 2048 + colb] = bv[r];
                    }
                    o.x = bv[0]; o.y = bv[1]; o.z = bv[2]; o.w = bv[3];
                    int kcol = colb - 1024;
                    int bb = rowb >> 11;
                    *(ushort4*)&Ktb[((size_t)((bb * 16 + (kcol >> 6)) * 64 + (kcol & 63))) * 2048 + (rowb & 2047)] = o;
                } else {
                    int vcol = colb - 2048;
                    int bb = rowb >> 11;
                    ushort4 o;
                    o.x = f2bf(acc[m][n][0]); o.y = f2bf(acc[m][n][1]);
                    o.z = f2bf(acc[m][n][2]); o.w = f2bf(acc[m][n][3]);
                    *(ushort4*)&Vtb[((size_t)((bb * 16 + (vcol >> 6)) * 64 + (vcol & 63))) * 2048 + (rowb & 2047)] = o;
                }
            }
        }
}

// ---------------------------------------------------------------------------
// Phase A: per-chunk state delta. Block = (chunk c, bh), 128 thr = 2 waves.
// dS[v][k] = sum_{j in chunk} Vt[v][j] * Kt[k][j] * 2^(cref - a_j)  (bf16 out)
// dZ[k]    = sum_{j in chunk} Kt[k][j] * 2^(cref - a_j)             (f32 out)
// ---------------------------------------------------------------------------
__global__ __launch_bounds__(128)
void state_delta(const u16* __restrict__ Ktb, const u16* __restrict__ Vtb,
                 const float* __restrict__ CCg, const float* __restrict__ CJWg,
                 u16* __restrict__ dSg, float* __restrict__ dZg) {
    __shared__ u16 Kts[4096], Vts[4096];
    __shared__ float cjl[64];
    int c = blockIdx.x, bh = blockIdx.y;
    int j0 = c * 64;
    int t = threadIdx.x, w = t >> 6, lane = t & 63, l31 = lane & 31, hi = lane >> 5;
    const u16* ktg = Ktb + (size_t)(bh * 64) * 2048 + j0;
    const u16* vtg = Vtb + (size_t)(bh * 64) * 2048 + j0;
#pragma unroll
    for (int rnd = 0; rnd < 4; rnd++) {
        int cc_ = rnd * 128 + t; int row = cc_ >> 3; int ch = (cc_ & 7) ^ (row & 7);
        async16(&Kts[cc_ * 8], ktg + (size_t)row * 2048 + ch * 8);
        async16(&Vts[cc_ * 8], vtg + (size_t)row * 2048 + ch * 8);
    }
    if (t < 64) cjl[t] = CJWg[(size_t)bh * L_ + j0 + t];   // plain store (rule 21!)
    float cref = CCg[(size_t)bh * L_ + j0 + 63];
    __syncthreads();

    f32x16 zz16;
#pragma unroll
    for (int r = 0; r < 16; r++) zz16[r] = 0.f;
    int swz = l31 & 7;
    int vq = w;
    u16* base = dSg + (size_t)(bh * 32 + c) * 4096;

#pragma unroll
    for (int kq = 0; kq < 2; kq++) {
        f32x16 acc = zz16;
        float zs = 0.f;
#pragma unroll
        for (int ks = 0; ks < 4; ks++) {
            int ch = (ks * 2 + hi) ^ swz;
            bf16x8 kt = *(const bf16x8*)&Kts[(kq * 32 + l31) * 64 + ch * 8];
            bf16x8 vt = *(const bf16x8*)&Vts[(vq * 32 + l31) * 64 + ch * 8];
            union { unsigned u[4]; bf16x8 v; } kw;
#pragma unroll
            for (int e2 = 0; e2 < 4; e2++) {
                int jb = ks * 16 + hi * 8 + e2 * 2;
                float f0 = bf2f(kt[e2 * 2 + 0]) * fexp2(cref - cjl[jb]);
                float f1 = bf2f(kt[e2 * 2 + 1]) * fexp2(cref - cjl[jb + 1]);
                zs += f0 + f1;
                asm("v_cvt_pk_bf16_f32 %0, %1, %2" : "=v"(kw.u[e2]) : "v"(f0), "v"(f1));
            }
            acc = __builtin_amdgcn_mfma_f32_32x32x16_bf16(vt, kw.v, acc, 0, 0, 0);
        }
#pragma unroll
        for (int r = 0; r < 16; r++) {
            int v = vq * 32 + (r & 3) + 8 * (r >> 2) + 4 * hi;
            base[v * 64 + kq * 32 + l31] = f2bf(acc[r]);
        }
        if (w == 0) {
            zs += __shfl_xor(zs, 32, 64);
            if (hi == 0)
                dZg[(size_t)(bh * 32 + c) * 64 + kq * 32 + l31] = zs;
        }
    }
}

// ---------------------------------------------------------------------------
// Phase B: per-element scan over 32 chunks. Grid (32 bh, 9): y<8 = state
// slices (each thread 2 elements), y==8 = z (t<64). fp32 accum, bf16 S out.
// ---------------------------------------------------------------------------
__global__ __launch_bounds__(256)
void state_scan(const u16* __restrict__ dSg, const float* __restrict__ dZg,
                const float* __restrict__ CCg,
                u16* __restrict__ Sg, float* __restrict__ Zg) {
    __shared__ float lam[32];
    int bh = blockIdx.x, slice = blockIdx.y;
    int t = threadIdx.x;
    if (t < 32) {
        float cr = CCg[(size_t)bh * L_ + t * 64 + 63];
        float cp = t ? CCg[(size_t)bh * L_ + t * 64 - 1] : 0.f;
        lam[t] = t ? fexp2(cr - cp) : 0.f;
    }
    __syncthreads();
    if (slice < 8) {
        int eidx = slice * 512 + t * 2;
        float s0 = 0.f, s1 = 0.f;
#pragma unroll 8
        for (int c = 0; c < 32; c++) {
            unsigned d = *(const unsigned*)&dSg[(size_t)(bh * 32 + c) * 4096 + eidx];
            float l = lam[c];
            s0 = l * s0 + bf2f((short)(d & 0xffff));
            s1 = l * s1 + bf2f((short)(d >> 16));
            unsigned o;
            asm("v_cvt_pk_bf16_f32 %0, %1, %2" : "=v"(o) : "v"(s0), "v"(s1));
            *(unsigned*)&Sg[(size_t)(bh * 32 + c) * 4096 + eidx] = o;
        }
    } else if (t < 64) {
        float z = 0.f;
#pragma unroll 8
        for (int c = 0; c < 32; c++) {
            z = lam[c] * z + dZg[(size_t)(bh * 32 + c) * 64 + t];
            Zg[(size_t)(bh * 32 + c) * 64 + t] = z;
        }
    }
}

// ---------------------------------------------------------------------------
// Phase C: output. Block = (chunk c, bh), 128 thr = 2 waves x 32 i-rows.
// out_i = [ intra (triangular QK^T*decay @ V) + 2^(c_i - cref_{c-1}) Q_i@S_{c-1} ]
//         / [ intra_den + 2^(c_i - cref_{c-1}) Q_i.z_{c-1} + eps ]
// ---------------------------------------------------------------------------
__global__ __launch_bounds__(128)
void attn_out(const u16* __restrict__ QK, const u16* __restrict__ Vtb,
              const u16* __restrict__ Sg, const float* __restrict__ Zg,
              const float* __restrict__ CCg, const float* __restrict__ CJWg,
              u16* __restrict__ AOb) {
    __shared__ u16 Qs[4096], Ks[4096], Vts[4096], Ss[4096];
    __shared__ float ccl[64], cjl[64], zbl[64];
    int c = blockIdx.x, bh = blockIdx.y;
    int b = bh >> 4, h = bh & 15;
    int j0 = c * 64;
    int t = threadIdx.x, w = t >> 6, lane = t & 63, l31 = lane & 31, hi = lane >> 5;
    int w32 = w * 32;

    const u16* qkg = QK + (size_t)(b * L_ + j0) * 2048 + h * 64;
    const u16* vtg = Vtb + (size_t)(bh * 64) * 2048 + j0;
#pragma unroll
    for (int rnd = 0; rnd < 4; rnd++) {
        int cc_ = rnd * 128 + t; int row = cc_ >> 3; int ch = (cc_ & 7) ^ (row & 7);
        async16(&Qs[cc_ * 8],  qkg + (size_t)row * 2048 + ch * 8);
        async16(&Ks[cc_ * 8],  qkg + (size_t)row * 2048 + 1024 + ch * 8);
        async16(&Vts[cc_ * 8], vtg + (size_t)row * 2048 + ch * 8);
    }
    if (c) {
        const u16* sg = Sg + (size_t)(bh * 32 + c - 1) * 4096;
#pragma unroll
        for (int rnd = 0; rnd < 4; rnd++) {
            int cc_ = rnd * 128 + t; int row = cc_ >> 3; int ch = (cc_ & 7) ^ (row & 7);
            async16(&Ss[cc_ * 8], sg + row * 64 + ch * 8);
        }
        if (t < 64) zbl[t] = Zg[(size_t)(bh * 32 + c - 1) * 64 + t];  // plain store
    }
    // plain per-lane stores for the small fp32 arrays (rule 21: async16 with
    // a non-lane0 base writes base+lane*16, NOT per-lane scatter)
    if (t < 64) {
        ccl[t] = CCg[(size_t)bh * L_ + j0 + t];
        cjl[t] = CJWg[(size_t)bh * L_ + j0 + t];
    }
    float cpv = c ? CCg[(size_t)bh * L_ + j0 - 1] : 0.f;
    __syncthreads();

    f32x16 zz16;
#pragma unroll
    for (int r = 0; r < 16; r++) zz16[r] = 0.f;
    int swz = l31 & 7;

    // Q fragments (A- and B-operand layouts are identical: lane&31 = row)
    bf16x8 qb[4];
#pragma unroll
    for (int ks = 0; ks < 4; ks++) {
        int ch = (ks * 2 + hi) ^ swz;
        qb[ks] = *(const bf16x8*)&Qs[(w32 + l31) * 64 + ch * 8];
    }
    float ci = ccl[w32 + l31];

    // ---- intra QK^T (swapped): st = S^T frag, i = l31 col ----
    f32x16 st[2];
    st[0] = zz16; st[1] = zz16;
    __builtin_amdgcn_s_setprio(1);
#pragma unroll
    for (int ks = 0; ks < 4; ks++) {
        int ch = (ks * 2 + hi) ^ swz;
        bf16x8 k0 = *(const bf16x8*)&Ks[l31 * 64 + ch * 8];
        bf16x8 k1 = *(const bf16x8*)&Ks[(32 + l31) * 64 + ch * 8];
        st[0] = __builtin_amdgcn_mfma_f32_32x32x16_bf16(k0, qb[ks], st[0], 0, 0, 0);
        st[1] = __builtin_amdgcn_mfma_f32_32x32x16_bf16(k1, qb[ks], st[1], 0, 0, 0);
    }
    __builtin_amdgcn_s_setprio(0);

    // ---- P build (triangular), pack bf16 ----
    unsigned pk[2][4][2];
    float dloc = 0.f;
    int lim = w32 + l31;
#pragma unroll
    for (int n = 0; n < 2; n++) {
#pragma unroll
        for (int rq = 0; rq < 4; rq++) {
            float4 cj4 = *(const float4*)&cjl[n * 32 + rq * 8 + hi * 4];
            float e0 = st[n][rq * 4 + 0] * fexp2(ci - cj4.x);
            float e1 = st[n][rq * 4 + 1] * fexp2(ci - cj4.y);
            float e2 = st[n][rq * 4 + 2] * fexp2(ci - cj4.z);
            float e3 = st[n][rq * 4 + 3] * fexp2(ci - cj4.w);
            int jb = n * 32 + rq * 8 + hi * 4;
            e0 = (jb + 0 <= lim) ? e0 : 0.f;
            e1 = (jb + 1 <= lim) ? e1 : 0.f;
            e2 = (jb + 2 <= lim) ? e2 : 0.f;
            e3 = (jb + 3 <= lim) ? e3 : 0.f;
            dloc += (e0 + e1) + (e2 + e3);
            asm("v_cvt_pk_bf16_f32 %0, %1, %2" : "=v"(pk[n][rq][0]) : "v"(e0), "v"(e1));
            asm("v_cvt_pk_bf16_f32 %0, %1, %2" : "=v"(pk[n][rq][1]) : "v"(e2), "v"(e3));
        }
    }

    // ---- PV ----
    f32x16 acc0 = zz16, acc1 = zz16;
    __builtin_amdgcn_s_setprio(1);
#pragma unroll
    for (int wi = 0; wi < 4; wi++) {
        int n = wi >> 1, qA = 2 * (wi & 1), qB = qA + 1;
        unsigned a0 = pk[n][qA][0], b0 = pk[n][qB][0];
        unsigned a1 = pk[n][qA][1], b1 = pk[n][qB][1];
        asm volatile("v_permlane32_swap_b32 %0, %1" : "+v"(a0), "+v"(b0));
        asm volatile("v_permlane32_swap_b32 %0, %1" : "+v"(a1), "+v"(b1));
        union { unsigned u[4]; bf16x8 v; } aw;
        aw.u[0] = a0; aw.u[1] = a1; aw.u[2] = b0; aw.u[3] = b1;
        int jc = (wi * 2 + hi) ^ swz;
        bf16x8 v0 = *(const bf16x8*)&Vts[l31 * 64 + jc * 8];
        bf16x8 v1 = *(const bf16x8*)&Vts[(32 + l31) * 64 + jc * 8];
        acc0 = __builtin_amdgcn_mfma_f32_32x32x16_bf16(aw.v, v0, acc0, 0, 0, 0);
        acc1 = __builtin_amdgcn_mfma_f32_32x32x16_bf16(aw.v, v1, acc1, 0, 0, 0);
    }
    __builtin_amdgcn_s_setprio(0);

    // ---- inter: Q @ S_{c-1}, Q . z_{c-1} ----
    if (c) {
        f32x16 oi0 = zz16, oi1 = zz16;
        __builtin_amdgcn_s_setprio(1);
#pragma unroll
        for (int ks = 0; ks < 4; ks++) {
            int ch = (ks * 2 + hi) ^ swz;
            bf16x8 s0 = *(const bf16x8*)&Ss[l31 * 64 + ch * 8];
            bf16x8 s1 = *(const bf16x8*)&Ss[(32 + l31) * 64 + ch * 8];
            oi0 = __builtin_amdgcn_mfma_f32_32x32x16_bf16(qb[ks], s0, oi0, 0, 0, 0);
            oi1 = __builtin_amdgcn_mfma_f32_32x32x16_bf16(qb[ks], s1, oi1, 0, 0, 0);
        }
        __builtin_amdgcn_s_setprio(0);
#pragma unroll
        for (int r = 0; r < 16; r++) {
            int il = (r & 3) + 8 * (r >> 2) + 4 * hi;
            float sc = fexp2(ccl[w32 + il] - cpv);
            acc0[r] += sc * oi0[r];
            acc1[r] += sc * oi1[r];
        }
        float dq = 0.f;
#pragma unroll
        for (int ks = 0; ks < 4; ks++)
#pragma unroll
            for (int e = 0; e < 8; e++)
                dq += bf2f(qb[ks][e]) * zbl[ks * 16 + hi * 8 + e];
        dloc += fexp2(ci - cpv) * dq;
    }

    // ---- denominator broadcast + output ----
    float dl = dloc + __shfl_xor(dloc, 32, 64);
#pragma unroll
    for (int r = 0; r < 16; r++) {
        int il = (r & 3) + 8 * (r >> 2) + 4 * hi;
        float dv = __shfl(dl, il, 64);
        float inv = 1.f / (dv + 1e-6f);
        int ig = j0 + w32 + il;
        AOb[(size_t)(b * L_ + ig) * D_ + h * DH + l31]      = f2bf(acc0[r] * inv);
        AOb[(size_t)(b * L_ + ig) * D_ + h * DH + 32 + l31] = f2bf(acc1[r] * inv);
    }
}

// ---------------------------------------------------------------------------
extern "C" void kernel_launch(void* const* d_in, const int* in_sizes, int n_in,
                              void* d_out, int out_size, void* d_ws, size_t ws_size,
                              hipStream_t stream) {
    const float* x  = (const float*)d_in[0];
    const float* Wq = (const float*)d_in[1];
    const float* Wk = (const float*)d_in[2];
    const float* Wv = (const float*)d_in[3];
    const float* Wo = (const float*)d_in[4];
    const float* Ww = (const float*)d_in[5];
    const float* bw = (const float*)d_in[6];
    const float* We = (const float*)d_in[7];
    const float* be = (const float*)d_in[8];
    float* out = (float*)d_out;

    char* wsb = (char*)d_ws;
    u16* xb   = (u16*)(wsb);                        // 8MB (dead after QKV gemm)
    u16* Sg   = xb;                                 // 8MB, reuses xb region
    u16* Wcat = (u16*)(wsb + ((size_t)8  << 20));   // 8MB  [Wq;Wk;Wv;Wo] bf16
    u16* QK   = (u16*)(wsb + ((size_t)16 << 20));   // 16MB [4096][2048] Q|K phi'd
    u16* Vtb  = (u16*)(wsb + ((size_t)32 << 20));   // 8MB  [B*H*64][2048]
    u16* Ktb  = (u16*)(wsb + ((size_t)40 << 20));   // 8MB  [B*H*64][2048]
    u16* AOb  = (u16*)(wsb + ((size_t)48 << 20));   // 8MB  [4096][1024]
    u16* dSg  = AOb;                                // 8MB, consumed before AOb written
    float* GLOG = (float*)(wsb + ((size_t)56 << 20));
    float* LWG  = GLOG + 65536;
    float* CC   = LWG  + 65536;
    float* CJW  = CC   + 65536;
    float* dZg  = CJW  + 65536;   // 256KB
    float* Zg   = dZg  + 65536;   // 256KB
    u16*  WG2  = (u16*)(Zg + 65536);   // 256KB [128][1024] bf16 gate B-tile

    // 1) pure casts: weights, x, gate-weights
    prep_kernel<<<8224, 256, 0, stream>>>(
        x, Wq, Wk, Wv, Wo, Ww, We, Wcat, xb, WG2);

    // 2) fused QKV + gates projection (32 m x 25 n, 2D-XCD mapped)
    gemm_fused<<<32 * 25, 256, 0, stream>>>(
        xb, Wcat, QK, Ktb, Vtb, WG2, bw, be, GLOG, LWG, QKV_N, D_, 2);

    // 3) log-decay scan
    scan_kernel<<<B_ * H_, 64, 0, stream>>>(GLOG, LWG, CC, CJW);

    // 4-6) chunked linear attention
    state_delta<<<dim3(32, B_ * H_), 128, 0, stream>>>(Ktb, Vtb, CC, CJW, dSg, dZg);
    state_scan<<<dim3(B_ * H_, 9), 256, 0, stream>>>(dSg, dZg, CC, Sg, Zg);
    attn_out<<<dim3(32, B_ * H_), 128, 0, stream>>>(QK, Vtb, Sg, Zg, CC, CJW, AOb);

    // 7) output projection (32 m x 8 n, 2D-XCD mapped)
    gemm_fused<<<32 * 8, 256, 0, stream>>>(
        AOb, Wcat + (size_t)3072 * 1024, out, Ktb, Vtb, WG2, bw, be, GLOG, LWG,
        D_, D_, 1);
}

// Round 17
// 108.431 us; speedup vs baseline: 1.0714x; 1.0342x over previous
//
#include <hip/hip_runtime.h>
#include <hip/hip_bf16.h>
#include <math.h>

#define B_ 2
#define L_ 2048
#define D_ 1024
#define H_ 16
#define DH 64
#define ML (B_*L_)      // 4096
#define QKV_N 3072

typedef __attribute__((ext_vector_type(8)))  short bf16x8;
typedef __attribute__((ext_vector_type(4)))  float f32x4;
typedef __attribute__((ext_vector_type(16))) float f32x16;
typedef unsigned short u16;

__device__ __forceinline__ u16 f2bf(float f) {
    union { float f; unsigned u; } v; v.f = f;
    unsigned r = (v.u + 0x7FFFu + ((v.u >> 16) & 1u)) >> 16;
    return (u16)r;
}

__device__ __forceinline__ float bf2f(short s) {
    union { unsigned u; float f; } v;
    v.u = ((unsigned)(unsigned short)s) << 16;
    return v.f;
}

__device__ __forceinline__ float fexp2(float x) {
    float r; asm("v_exp_f32 %0, %1" : "=v"(r) : "v"(x)); return r;
}

// async global->LDS, 16B per lane. HW semantics: LDS dest = readfirstlane(ptr)
// + lane*16 -> ONLY use with full waves whose lane-0 pointer is the base.
__device__ __forceinline__ void async16(void* lds, const void* g) {
    __builtin_amdgcn_global_load_lds(
        (__attribute__((address_space(1))) unsigned int*)g,
        (__attribute__((address_space(3))) unsigned int*)lds,
        16, 0, 0);
}

// 2D XCD-aware tile decode (MT must be 32 = 4 m-tiles per XCD x 8 XCDs).
__device__ __forceinline__ void xcd_decode(int id, int& mt, int& nt) {
    int xcd = id & 7;
    int r = id >> 3;
    nt = r >> 2;
    mt = (xcd << 2) | (r & 3);
}

// ---------------------------------------------------------------------------
// prep_kernel: pure casts (memory-bound).
//   blocks 0..4095    : Wq|Wk|Wv|Wo -> Wcat bf16 [4096][1024]
//   blocks 4096..8191 : x -> xb bf16 [4096][1024]
//   blocks 8192..8223 : [Ww;We] -> WG2 bf16 rows 0..31 (gate B-tile)
// ---------------------------------------------------------------------------
__global__ __launch_bounds__(256)
void prep_kernel(const float* __restrict__ x,
                 const float* __restrict__ Wq, const float* __restrict__ Wk,
                 const float* __restrict__ Wv, const float* __restrict__ Wo,
                 const float* __restrict__ Ww, const float* __restrict__ We,
                 u16* __restrict__ Wcat, u16* __restrict__ xb,
                 u16* __restrict__ WG2) {
    int blk = blockIdx.x, t = threadIdx.x;
    if (blk < 4096) {
        int i = (blk * 256 + t) * 4;
        int sel = i >> 20;
        const float* s = sel == 0 ? Wq : sel == 1 ? Wk : sel == 2 ? Wv : Wo;
        float4 v = *(const float4*)(s + (i & 1048575));
        ushort4 o;
        o.x = f2bf(v.x); o.y = f2bf(v.y); o.z = f2bf(v.z); o.w = f2bf(v.w);
        *(ushort4*)(Wcat + i) = o;
    } else if (blk < 8192) {
        int i = ((blk - 4096) * 256 + t) * 4;
        float4 v = *(const float4*)(x + i);
        ushort4 o;
        o.x = f2bf(v.x); o.y = f2bf(v.y); o.z = f2bf(v.z); o.w = f2bf(v.w);
        *(ushort4*)(xb + i) = o;
    } else {
        int i = ((blk - 8192) * 256 + t) * 4;    // 0..32767
        const float* s = (i < 16384) ? (Ww + i) : (We + i - 16384);
        float4 v = *(const float4*)s;
        ushort4 o;
        o.x = f2bf(v.x); o.y = f2bf(v.y); o.z = f2bf(v.z); o.w = f2bf(v.w);
        *(ushort4*)(WG2 + i) = o;
    }
}

// ---------------------------------------------------------------------------
// Inclusive scan per (b,h): CC = cumsum(GLOG); CJW = CC - LWG   (log2 domain)
// ---------------------------------------------------------------------------
__global__ __launch_bounds__(64)
void scan_kernel(const float* __restrict__ GLOG, const float* __restrict__ LWG,
                 float* __restrict__ CC, float* __restrict__ CJW) {
    int bh = blockIdx.x;
    int lane = threadIdx.x;
    const float* src = GLOG + (size_t)bh * L_;
    const float* lw  = LWG  + (size_t)bh * L_;
    float* dst  = CC  + (size_t)bh * L_;
    float* dstw = CJW + (size_t)bh * L_;
    float running = 0.f;
    for (int base = 0; base < L_; base += 64) {
        float v = src[base + lane];
#pragma unroll
        for (int off = 1; off < 64; off <<= 1) {
            float u = __shfl_up(v, off, 64);
            if (lane >= off) v += u;
        }
        float c = running + v;
        dst[base + lane]  = c;
        dstw[base + lane] = c - lw[base + lane];
        running += __shfl(v, 63, 64);
    }
}

// ---------------------------------------------------------------------------
// QKV+gates GEMM: 128x128 tile, BK=64, 4 waves, 2-phase dbuf, XOR-swizzled
// LDS (T2/rule21), 2D XCD-aware tile map.
// nt<8  -> phi+bf16 to QK (Q cols); 8<=nt<16 -> phi+bf16 to QK (K) + Ktb^T;
// 16<=nt<24 -> V -> Vtb^T; nt==24 -> gate tile (B=WG2) -> LWG/GLOG (log2).
// ---------------------------------------------------------------------------
__global__ __launch_bounds__(256)
void gemm_fused(const u16* __restrict__ A, const u16* __restrict__ Bw,
                u16* __restrict__ QKo, u16* __restrict__ Ktb,
                u16* __restrict__ Vtb, const u16* __restrict__ WG2,
                const float* __restrict__ bw, const float* __restrict__ be,
                float* __restrict__ GLOG, float* __restrict__ LWG,
                int K) {
    __shared__ u16 As[2][8192];   // [128 row][64 k]
    __shared__ u16 Bs[2][8192];
    int t = threadIdx.x;
    int lane = t & 63;
    int w = t >> 6, wm = w >> 1, wn = w & 1;
    int l15 = lane & 15, l4 = lane >> 4;
    int mt, nt;
    xcd_decode((int)blockIdx.x, mt, nt);
    int m0 = mt * 128, n0 = nt * 128;
    bool gate = (nt == 24);
    const u16* Bbase = gate ? WG2 : (Bw + (size_t)n0 * K);

    f32x4 zz = {0.f, 0.f, 0.f, 0.f};
    f32x4 acc[4][4];
#pragma unroll
    for (int m = 0; m < 4; m++)
#pragma unroll
        for (int n = 0; n < 4; n++) acc[m][n] = zz;

    auto STAGE = [&](int buf, int k0) {
#pragma unroll
        for (int i = 0; i < 4; i++) {
            int c = i * 256 + t;
            int row = c >> 3;
            int ch = (c & 7) ^ (row & 7);
            async16(&As[buf][c * 8], A     + (size_t)(m0 + row) * K + k0 + ch * 8);
            async16(&Bs[buf][c * 8], Bbase + (size_t)row * K + k0 + ch * 8);
        }
    };

    STAGE(0, 0);
    __syncthreads();

    int KT = K >> 6, cur = 0;
    for (int kt = 0; kt < KT; kt++) {
        if (kt + 1 < KT) STAGE(cur ^ 1, (kt + 1) << 6);

        bf16x8 af[4][2], bfr[4][2];
#pragma unroll
        for (int ks = 0; ks < 2; ks++) {
#pragma unroll
            for (int m = 0; m < 4; m++) {
                int row = wm * 64 + m * 16 + l15;
                int ch = (l4 + 4 * ks) ^ (row & 7);
                af[m][ks] = *(const bf16x8*)&As[cur][row * 64 + ch * 8];
            }
#pragma unroll
            for (int n = 0; n < 4; n++) {
                int row = wn * 64 + n * 16 + l15;
                int ch = (l4 + 4 * ks) ^ (row & 7);
                bfr[n][ks] = *(const bf16x8*)&Bs[cur][row * 64 + ch * 8];
            }
        }
#pragma unroll
        for (int m = 0; m < 4; m++)
#pragma unroll
            for (int n = 0; n < 4; n++) {
                acc[m][n] = __builtin_amdgcn_mfma_f32_16x16x32_bf16(af[m][0], bfr[n][0], acc[m][n], 0, 0, 0);
                acc[m][n] = __builtin_amdgcn_mfma_f32_16x16x32_bf16(af[m][1], bfr[n][1], acc[m][n], 0, 0, 0);
            }

        __syncthreads();
        cur ^= 1;
    }

    if (gate) {
        // gate epilogue: only cols 0..31 of this tile are live
#pragma unroll
        for (int m = 0; m < 4; m++)
#pragma unroll
            for (int n = 0; n < 4; n++) {
                int g = wn * 64 + n * 16 + l15;
                if (g < 32) {
                    int h = g & 15;
                    int rowb = m0 + wm * 64 + m * 16 + l4 * 4;
#pragma unroll
                    for (int r = 0; r < 4; r++) {
                        int row = rowb + r;
                        size_t idx = ((size_t)((row >> 11) * 16 + h)) * 2048 + (row & 2047);
                        float val = acc[m][n][r];
                        if (g < 16) {
                            float wgv = 1.f / (1.f + __expf(-(val + bw[h])));
                            LWG[idx] = __log2f(wgv);
                        } else {
                            float egv = 1.f / (1.f + __expf(-(val + be[h])));
                            GLOG[idx] = __log2f((1.f - egv) * 0.95f + 1e-8f);
                        }
                    }
                }
            }
        return;
    }

#pragma unroll
    for (int m = 0; m < 4; m++)
#pragma unroll
        for (int n = 0; n < 4; n++) {
            int colb = n0 + wn * 64 + n * 16 + l15;
            int rowb = m0 + wm * 64 + m * 16 + l4 * 4;
            if (colb < 1024) {
#pragma unroll
                for (int r = 0; r < 4; r++) {
                    float c = acc[m][n][r];
                    c = (c > 0.f) ? (c + 1.f) : __expf(c);
                    QKo[(size_t)(rowb + r) * 2048 + colb] = f2bf(c);
                }
            } else if (colb < 2048) {
                ushort4 o;
                u16 bv[4];
#pragma unroll
                for (int r = 0; r < 4; r++) {
                    float c = acc[m][n][r];
                    c = (c > 0.f) ? (c + 1.f) : __expf(c);
                    bv[r] = f2bf(c);
                    QKo[(size_t)(rowb + r) * 2048 + colb] = bv[r];
                }
                o.x = bv[0]; o.y = bv[1]; o.z = bv[2]; o.w = bv[3];
                int kcol = colb - 1024;
                int bb = rowb >> 11;
                *(ushort4*)&Ktb[((size_t)((bb * 16 + (kcol >> 6)) * 64 + (kcol & 63))) * 2048 + (rowb & 2047)] = o;
            } else {
                int vcol = colb - 2048;
                int bb = rowb >> 11;
                ushort4 o;
                o.x = f2bf(acc[m][n][0]); o.y = f2bf(acc[m][n][1]);
                o.z = f2bf(acc[m][n][2]); o.w = f2bf(acc[m][n][3]);
                *(ushort4*)&Vtb[((size_t)((bb * 16 + (vcol >> 6)) * 64 + (vcol & 63))) * 2048 + (rowb & 2047)] = o;
            }
        }
}

// ---------------------------------------------------------------------------
// Wo GEMM: 64x128 tile, BK=64, 4 waves (2m x 2n of 32x64), 2-phase dbuf,
// XOR-swizzled LDS. 48KB LDS -> 3 blocks/CU, 512 blocks all resident
// (fixes the 1-block/CU occupancy of the 128^2 grid at 256 blocks).
// ---------------------------------------------------------------------------
__global__ __launch_bounds__(256)
void gemm_wo64(const u16* __restrict__ A, const u16* __restrict__ Bw,
               float* __restrict__ Cout, int MT, int N, int K) {
    __shared__ u16 As[2][4096];   // [64 row][64 k]  8KB each
    __shared__ u16 Bs[2][8192];   // [128 row][64 k] 16KB each
    int t = threadIdx.x;
    int id = (int)blockIdx.x;
    int lane = t & 63;
    int w = t >> 6, wm = w >> 1, wn = w & 1;
    int l15 = lane & 15, l4 = lane >> 4;
    int m0 = (id % MT) * 64, n0 = (id / MT) * 128;

    f32x4 zz = {0.f, 0.f, 0.f, 0.f};
    f32x4 acc[2][4];
#pragma unroll
    for (int m = 0; m < 2; m++)
#pragma unroll
        for (int n = 0; n < 4; n++) acc[m][n] = zz;

    auto STAGE = [&](int buf, int k0) {
#pragma unroll
        for (int i = 0; i < 2; i++) {            // A: 512 chunks
            int c = i * 256 + t;
            int row = c >> 3;
            int ch = (c & 7) ^ (row & 7);
            async16(&As[buf][c * 8], A + (size_t)(m0 + row) * K + k0 + ch * 8);
        }
#pragma unroll
        for (int i = 0; i < 4; i++) {            // B: 1024 chunks
            int c = i * 256 + t;
            int row = c >> 3;
            int ch = (c & 7) ^ (row & 7);
            async16(&Bs[buf][c * 8], Bw + (size_t)(n0 + row) * K + k0 + ch * 8);
        }
    };

    STAGE(0, 0);
    __syncthreads();

    int KT = K >> 6, cur = 0;
    for (int kt = 0; kt < KT; kt++) {
        if (kt + 1 < KT) STAGE(cur ^ 1, (kt + 1) << 6);

        bf16x8 af[2][2], bfr[4][2];
#pragma unroll
        for (int ks = 0; ks < 2; ks++) {
#pragma unroll
            for (int m = 0; m < 2; m++) {
                int row = wm * 32 + m * 16 + l15;      // 0..63
                int ch = (l4 + 4 * ks) ^ (row & 7);
                af[m][ks] = *(const bf16x8*)&As[cur][row * 64 + ch * 8];
            }
#pragma unroll
            for (int n = 0; n < 4; n++) {
                int row = wn * 64 + n * 16 + l15;      // 0..127
                int ch = (l4 + 4 * ks) ^ (row & 7);
                bfr[n][ks] = *(const bf16x8*)&Bs[cur][row * 64 + ch * 8];
            }
        }
#pragma unroll
        for (int m = 0; m < 2; m++)
#pragma unroll
            for (int n = 0; n < 4; n++) {
                acc[m][n] = __builtin_amdgcn_mfma_f32_16x16x32_bf16(af[m][0], bfr[n][0], acc[m][n], 0, 0, 0);
                acc[m][n] = __builtin_amdgcn_mfma_f32_16x16x32_bf16(af[m][1], bfr[n][1], acc[m][n], 0, 0, 0);
            }

        __syncthreads();
        cur ^= 1;
    }

#pragma unroll
    for (int m = 0; m < 2; m++)
#pragma unroll
        for (int n = 0; n < 4; n++) {
            int colb = n0 + wn * 64 + n * 16 + l15;
            int rowb = m0 + wm * 32 + m * 16 + l4 * 4;
#pragma unroll
            for (int r = 0; r < 4; r++)
                Cout[(size_t)(rowb + r) * N + colb] = acc[m][n][r];
        }
}

// ---------------------------------------------------------------------------
// Phase A: per-chunk state delta. Block = (chunk c, bh), 128 thr = 2 waves.
// dS[v][k] = sum_{j in chunk} Vt[v][j] * Kt[k][j] * 2^(cref - a_j)  (bf16 out)
// dZ[k]    = sum_{j in chunk} Kt[k][j] * 2^(cref - a_j)             (f32 out)
// ---------------------------------------------------------------------------
__global__ __launch_bounds__(128)
void state_delta(const u16* __restrict__ Ktb, const u16* __restrict__ Vtb,
                 const float* __restrict__ CCg, const float* __restrict__ CJWg,
                 u16* __restrict__ dSg, float* __restrict__ dZg) {
    __shared__ u16 Kts[4096], Vts[4096];
    __shared__ float cjl[64];
    int c = blockIdx.x, bh = blockIdx.y;
    int j0 = c * 64;
    int t = threadIdx.x, w = t >> 6, lane = t & 63, l31 = lane & 31, hi = lane >> 5;
    const u16* ktg = Ktb + (size_t)(bh * 64) * 2048 + j0;
    const u16* vtg = Vtb + (size_t)(bh * 64) * 2048 + j0;
#pragma unroll
    for (int rnd = 0; rnd < 4; rnd++) {
        int cc_ = rnd * 128 + t; int row = cc_ >> 3; int ch = (cc_ & 7) ^ (row & 7);
        async16(&Kts[cc_ * 8], ktg + (size_t)row * 2048 + ch * 8);
        async16(&Vts[cc_ * 8], vtg + (size_t)row * 2048 + ch * 8);
    }
    if (t < 64) cjl[t] = CJWg[(size_t)bh * L_ + j0 + t];   // plain store (rule 21!)
    float cref = CCg[(size_t)bh * L_ + j0 + 63];
    __syncthreads();

    f32x16 zz16;
#pragma unroll
    for (int r = 0; r < 16; r++) zz16[r] = 0.f;
    int swz = l31 & 7;
    int vq = w;
    u16* base = dSg + (size_t)(bh * 32 + c) * 4096;

#pragma unroll
    for (int kq = 0; kq < 2; kq++) {
        f32x16 acc = zz16;
        float zs = 0.f;
#pragma unroll
        for (int ks = 0; ks < 4; ks++) {
            int ch = (ks * 2 + hi) ^ swz;
            bf16x8 kt = *(const bf16x8*)&Kts[(kq * 32 + l31) * 64 + ch * 8];
            bf16x8 vt = *(const bf16x8*)&Vts[(vq * 32 + l31) * 64 + ch * 8];
            union { unsigned u[4]; bf16x8 v; } kw;
#pragma unroll
            for (int e2 = 0; e2 < 4; e2++) {
                int jb = ks * 16 + hi * 8 + e2 * 2;
                float f0 = bf2f(kt[e2 * 2 + 0]) * fexp2(cref - cjl[jb]);
                float f1 = bf2f(kt[e2 * 2 + 1]) * fexp2(cref - cjl[jb + 1]);
                zs += f0 + f1;
                asm("v_cvt_pk_bf16_f32 %0, %1, %2" : "=v"(kw.u[e2]) : "v"(f0), "v"(f1));
            }
            acc = __builtin_amdgcn_mfma_f32_32x32x16_bf16(vt, kw.v, acc, 0, 0, 0);
        }
#pragma unroll
        for (int r = 0; r < 16; r++) {
            int v = vq * 32 + (r & 3) + 8 * (r >> 2) + 4 * hi;
            base[v * 64 + kq * 32 + l31] = f2bf(acc[r]);
        }
        if (w == 0) {
            zs += __shfl_xor(zs, 32, 64);
            if (hi == 0)
                dZg[(size_t)(bh * 32 + c) * 64 + kq * 32 + l31] = zs;
        }
    }
}

// ---------------------------------------------------------------------------
// Phase B: per-element scan over 32 chunks. Grid (32 bh, 9): y<8 = state
// slices (each thread 2 elements), y==8 = z (t<64). fp32 accum, bf16 S out.
// ---------------------------------------------------------------------------
__global__ __launch_bounds__(256)
void state_scan(const u16* __restrict__ dSg, const float* __restrict__ dZg,
                const float* __restrict__ CCg,
                u16* __restrict__ Sg, float* __restrict__ Zg) {
    __shared__ float lam[32];
    int bh = blockIdx.x, slice = blockIdx.y;
    int t = threadIdx.x;
    if (t < 32) {
        float cr = CCg[(size_t)bh * L_ + t * 64 + 63];
        float cp = t ? CCg[(size_t)bh * L_ + t * 64 - 1] : 0.f;
        lam[t] = t ? fexp2(cr - cp) : 0.f;
    }
    __syncthreads();
    if (slice < 8) {
        int eidx = slice * 512 + t * 2;
        float s0 = 0.f, s1 = 0.f;
#pragma unroll 8
        for (int c = 0; c < 32; c++) {
            unsigned d = *(const unsigned*)&dSg[(size_t)(bh * 32 + c) * 4096 + eidx];
            float l = lam[c];
            s0 = l * s0 + bf2f((short)(d & 0xffff));
            s1 = l * s1 + bf2f((short)(d >> 16));
            unsigned o;
            asm("v_cvt_pk_bf16_f32 %0, %1, %2" : "=v"(o) : "v"(s0), "v"(s1));
            *(unsigned*)&Sg[(size_t)(bh * 32 + c) * 4096 + eidx] = o;
        }
    } else if (t < 64) {
        float z = 0.f;
#pragma unroll 8
        for (int c = 0; c < 32; c++) {
            z = lam[c] * z + dZg[(size_t)(bh * 32 + c) * 64 + t];
            Zg[(size_t)(bh * 32 + c) * 64 + t] = z;
        }
    }
}

// ---------------------------------------------------------------------------
// Phase C: output. Block = (chunk c, bh), 128 thr = 2 waves x 32 i-rows.
// out_i = [ intra (triangular QK^T*decay @ V) + 2^(c_i - cref_{c-1}) Q_i@S_{c-1} ]
//         / [ intra_den + 2^(c_i - cref_{c-1}) Q_i.z_{c-1} + eps ]
// ---------------------------------------------------------------------------
__global__ __launch_bounds__(128)
void attn_out(const u16* __restrict__ QK, const u16* __restrict__ Vtb,
              const u16* __restrict__ Sg, const float* __restrict__ Zg,
              const float* __restrict__ CCg, const float* __restrict__ CJWg,
              u16* __restrict__ AOb) {
    __shared__ u16 Qs[4096], Ks[4096], Vts[4096], Ss[4096];
    __shared__ float ccl[64], cjl[64], zbl[64];
    int c = blockIdx.x, bh = blockIdx.y;
    int b = bh >> 4, h = bh & 15;
    int j0 = c * 64;
    int t = threadIdx.x, w = t >> 6, lane = t & 63, l31 = lane & 31, hi = lane >> 5;
    int w32 = w * 32;

    const u16* qkg = QK + (size_t)(b * L_ + j0) * 2048 + h * 64;
    const u16* vtg = Vtb + (size_t)(bh * 64) * 2048 + j0;
#pragma unroll
    for (int rnd = 0; rnd < 4; rnd++) {
        int cc_ = rnd * 128 + t; int row = cc_ >> 3; int ch = (cc_ & 7) ^ (row & 7);
        async16(&Qs[cc_ * 8],  qkg + (size_t)row * 2048 + ch * 8);
        async16(&Ks[cc_ * 8],  qkg + (size_t)row * 2048 + 1024 + ch * 8);
        async16(&Vts[cc_ * 8], vtg + (size_t)row * 2048 + ch * 8);
    }
    if (c) {
        const u16* sg = Sg + (size_t)(bh * 32 + c - 1) * 4096;
#pragma unroll
        for (int rnd = 0; rnd < 4; rnd++) {
            int cc_ = rnd * 128 + t; int row = cc_ >> 3; int ch = (cc_ & 7) ^ (row & 7);
            async16(&Ss[cc_ * 8], sg + row * 64 + ch * 8);
        }
        if (t < 64) zbl[t] = Zg[(size_t)(bh * 32 + c - 1) * 64 + t];  // plain store
    }
    // plain per-lane stores for the small fp32 arrays (rule 21: async16 with
    // a non-lane0 base writes base+lane*16, NOT per-lane scatter)
    if (t < 64) {
        ccl[t] = CCg[(size_t)bh * L_ + j0 + t];
        cjl[t] = CJWg[(size_t)bh * L_ + j0 + t];
    }
    float cpv = c ? CCg[(size_t)bh * L_ + j0 - 1] : 0.f;
    __syncthreads();

    f32x16 zz16;
#pragma unroll
    for (int r = 0; r < 16; r++) zz16[r] = 0.f;
    int swz = l31 & 7;

    // Q fragments (A- and B-operand layouts are identical: lane&31 = row)
    bf16x8 qb[4];
#pragma unroll
    for (int ks = 0; ks < 4; ks++) {
        int ch = (ks * 2 + hi) ^ swz;
        qb[ks] = *(const bf16x8*)&Qs[(w32 + l31) * 64 + ch * 8];
    }
    float ci = ccl[w32 + l31];

    // ---- intra QK^T (swapped): st = S^T frag, i = l31 col ----
    f32x16 st[2];
    st[0] = zz16; st[1] = zz16;
    __builtin_amdgcn_s_setprio(1);
#pragma unroll
    for (int ks = 0; ks < 4; ks++) {
        int ch = (ks * 2 + hi) ^ swz;
        bf16x8 k0 = *(const bf16x8*)&Ks[l31 * 64 + ch * 8];
        bf16x8 k1 = *(const bf16x8*)&Ks[(32 + l31) * 64 + ch * 8];
        st[0] = __builtin_amdgcn_mfma_f32_32x32x16_bf16(k0, qb[ks], st[0], 0, 0, 0);
        st[1] = __builtin_amdgcn_mfma_f32_32x32x16_bf16(k1, qb[ks], st[1], 0, 0, 0);
    }
    __builtin_amdgcn_s_setprio(0);

    // ---- P build (triangular), pack bf16 ----
    unsigned pk[2][4][2];
    float dloc = 0.f;
    int lim = w32 + l31;
#pragma unroll
    for (int n = 0; n < 2; n++) {
#pragma unroll
        for (int rq = 0; rq < 4; rq++) {
            float4 cj4 = *(const float4*)&cjl[n * 32 + rq * 8 + hi * 4];
            float e0 = st[n][rq * 4 + 0] * fexp2(ci - cj4.x);
            float e1 = st[n][rq * 4 + 1] * fexp2(ci - cj4.y);
            float e2 = st[n][rq * 4 + 2] * fexp2(ci - cj4.z);
            float e3 = st[n][rq * 4 + 3] * fexp2(ci - cj4.w);
            int jb = n * 32 + rq * 8 + hi * 4;
            e0 = (jb + 0 <= lim) ? e0 : 0.f;
            e1 = (jb + 1 <= lim) ? e1 : 0.f;
            e2 = (jb + 2 <= lim) ? e2 : 0.f;
            e3 = (jb + 3 <= lim) ? e3 : 0.f;
            dloc += (e0 + e1) + (e2 + e3);
            asm("v_cvt_pk_bf16_f32 %0, %1, %2" : "=v"(pk[n][rq][0]) : "v"(e0), "v"(e1));
            asm("v_cvt_pk_bf16_f32 %0, %1, %2" : "=v"(pk[n][rq][1]) : "v"(e2), "v"(e3));
        }
    }

    // ---- PV ----
    f32x16 acc0 = zz16, acc1 = zz16;
    __builtin_amdgcn_s_setprio(1);
#pragma unroll
    for (int wi = 0; wi < 4; wi++) {
        int n = wi >> 1, qA = 2 * (wi & 1), qB = qA + 1;
        unsigned a0 = pk[n][qA][0], b0 = pk[n][qB][0];
        unsigned a1 = pk[n][qA][1], b1 = pk[n][qB][1];
        asm volatile("v_permlane32_swap_b32 %0, %1" : "+v"(a0), "+v"(b0));
        asm volatile("v_permlane32_swap_b32 %0, %1" : "+v"(a1), "+v"(b1));
        union { unsigned u[4]; bf16x8 v; } aw;
        aw.u[0] = a0; aw.u[1] = a1; aw.u[2] = b0; aw.u[3] = b1;
        int jc = (wi * 2 + hi) ^ swz;
        bf16x8 v0 = *(const bf16x8*)&Vts[l31 * 64 + jc * 8];
        bf16x8 v1 = *(const bf16x8*)&Vts[(32 + l31) * 64 + jc * 8];
        acc0 = __builtin_amdgcn_mfma_f32_32x32x16_bf16(aw.v, v0, acc0, 0, 0, 0);
        acc1 = __builtin_amdgcn_mfma_f32_32x32x16_bf16(aw.v, v1, acc1, 0, 0, 0);
    }
    __builtin_amdgcn_s_setprio(0);

    // ---- inter: Q @ S_{c-1}, Q . z_{c-1} ----
    if (c) {
        f32x16 oi0 = zz16, oi1 = zz16;
        __builtin_amdgcn_s_setprio(1);
#pragma unroll
        for (int ks = 0; ks < 4; ks++) {
            int ch = (ks * 2 + hi) ^ swz;
            bf16x8 s0 = *(const bf16x8*)&Ss[l31 * 64 + ch * 8];
            bf16x8 s1 = *(const bf16x8*)&Ss[(32 + l31) * 64 + ch * 8];
            oi0 = __builtin_amdgcn_mfma_f32_32x32x16_bf16(qb[ks], s0, oi0, 0, 0, 0);
            oi1 = __builtin_amdgcn_mfma_f32_32x32x16_bf16(qb[ks], s1, oi1, 0, 0, 0);
        }
        __builtin_amdgcn_s_setprio(0);
#pragma unroll
        for (int r = 0; r < 16; r++) {
            int il = (r & 3) + 8 * (r >> 2) + 4 * hi;
            float sc = fexp2(ccl[w32 + il] - cpv);
            acc0[r] += sc * oi0[r];
            acc1[r] += sc * oi1[r];
        }
        float dq = 0.f;
#pragma unroll
        for (int ks = 0; ks < 4; ks++)
#pragma unroll
            for (int e = 0; e < 8; e++)
                dq += bf2f(qb[ks][e]) * zbl[ks * 16 + hi * 8 + e];
        dloc += fexp2(ci - cpv) * dq;
    }

    // ---- denominator broadcast + output ----
    float dl = dloc + __shfl_xor(dloc, 32, 64);
#pragma unroll
    for (int r = 0; r < 16; r++) {
        int il = (r & 3) + 8 * (r >> 2) + 4 * hi;
        float dv = __shfl(dl, il, 64);
        float inv = 1.f / (dv + 1e-6f);
        int ig = j0 + w32 + il;
        AOb[(size_t)(b * L_ + ig) * D_ + h * DH + l31]      = f2bf(acc0[r] * inv);
        AOb[(size_t)(b * L_ + ig) * D_ + h * DH + 32 + l31] = f2bf(acc1[r] * inv);
    }
}

// ---------------------------------------------------------------------------
extern "C" void kernel_launch(void* const* d_in, const int* in_sizes, int n_in,
                              void* d_out, int out_size, void* d_ws, size_t ws_size,
                              hipStream_t stream) {
    const float* x  = (const float*)d_in[0];
    const float* Wq = (const float*)d_in[1];
    const float* Wk = (const float*)d_in[2];
    const float* Wv = (const float*)d_in[3];
    const float* Wo = (const float*)d_in[4];
    const float* Ww = (const float*)d_in[5];
    const float* bw = (const float*)d_in[6];
    const float* We = (const float*)d_in[7];
    const float* be = (const float*)d_in[8];
    float* out = (float*)d_out;

    char* wsb = (char*)d_ws;
    u16* xb   = (u16*)(wsb);                        // 8MB (dead after QKV gemm)
    u16* Sg   = xb;                                 // 8MB, reuses xb region
    u16* Wcat = (u16*)(wsb + ((size_t)8  << 20));   // 8MB  [Wq;Wk;Wv;Wo] bf16
    u16* QK   = (u16*)(wsb + ((size_t)16 << 20));   // 16MB [4096][2048] Q|K phi'd
    u16* Vtb  = (u16*)(wsb + ((size_t)32 << 20));   // 8MB  [B*H*64][2048]
    u16* Ktb  = (u16*)(wsb + ((size_t)40 << 20));   // 8MB  [B*H*64][2048]
    u16* AOb  = (u16*)(wsb + ((size_t)48 << 20));   // 8MB  [4096][1024]
    u16* dSg  = AOb;                                // 8MB, consumed before AOb written
    float* GLOG = (float*)(wsb + ((size_t)56 << 20));
    float* LWG  = GLOG + 65536;
    float* CC   = LWG  + 65536;
    float* CJW  = CC   + 65536;
    float* dZg  = CJW  + 65536;   // 256KB
    float* Zg   = dZg  + 65536;   // 256KB
    u16*  WG2  = (u16*)(Zg + 65536);   // 256KB [128][1024] bf16 gate B-tile

    // 1) pure casts: weights, x, gate-weights
    prep_kernel<<<8224, 256, 0, stream>>>(
        x, Wq, Wk, Wv, Wo, Ww, We, Wcat, xb, WG2);

    // 2) fused QKV + gates projection (32 m x 25 n, 2D-XCD mapped)
    gemm_fused<<<32 * 25, 256, 0, stream>>>(
        xb, Wcat, QK, Ktb, Vtb, WG2, bw, be, GLOG, LWG, D_);

    // 3) log-decay scan
    scan_kernel<<<B_ * H_, 64, 0, stream>>>(GLOG, LWG, CC, CJW);

    // 4-6) chunked linear attention
    state_delta<<<dim3(32, B_ * H_), 128, 0, stream>>>(Ktb, Vtb, CC, CJW, dSg, dZg);
    state_scan<<<dim3(B_ * H_, 9), 256, 0, stream>>>(dSg, dZg, CC, Sg, Zg);
    attn_out<<<dim3(32, B_ * H_), 128, 0, stream>>>(QK, Vtb, Sg, Zg, CC, CJW, AOb);

    // 7) output projection: 64x128 tiles, 512 blocks, 3 blocks/CU
    gemm_wo64<<<(ML / 64) * (D_ / 128), 256, 0, stream>>>(
        AOb, Wcat + (size_t)3072 * 1024, out, ML / 64, D_, D_);
}

// Round 18
// 98.769 us; speedup vs baseline: 1.1762x; 1.0978x over previous
//
#include <hip/hip_runtime.h>
#include <hip/hip_bf16.h>
#include <math.h>

#define B_ 2
#define L_ 2048
#define D_ 1024
#define H_ 16
#define DH 64
#define ML (B_*L_)      // 4096
#define QKV_N 3072

typedef __attribute__((ext_vector_type(8)))  short bf16x8;
typedef __attribute__((ext_vector_type(4)))  float f32x4;
typedef __attribute__((ext_vector_type(16))) float f32x16;
typedef unsigned short u16;

__device__ __forceinline__ u16 f2bf(float f) {
    union { float f; unsigned u; } v; v.f = f;
    unsigned r = (v.u + 0x7FFFu + ((v.u >> 16) & 1u)) >> 16;
    return (u16)r;
}

__device__ __forceinline__ float bf2f(short s) {
    union { unsigned u; float f; } v;
    v.u = ((unsigned)(unsigned short)s) << 16;
    return v.f;
}

__device__ __forceinline__ float fexp2(float x) {
    float r; asm("v_exp_f32 %0, %1" : "=v"(r) : "v"(x)); return r;
}

// async global->LDS, 16B per lane. HW semantics: LDS dest = readfirstlane(ptr)
// + lane*16 -> ONLY use with full waves whose lane-0 pointer is the base.
__device__ __forceinline__ void async16(void* lds, const void* g) {
    __builtin_amdgcn_global_load_lds(
        (__attribute__((address_space(1))) unsigned int*)g,
        (__attribute__((address_space(3))) unsigned int*)lds,
        16, 0, 0);
}

// 2D XCD-aware tile decode (MT must be 32 = 4 m-tiles per XCD x 8 XCDs).
__device__ __forceinline__ void xcd_decode(int id, int& mt, int& nt) {
    int xcd = id & 7;
    int r = id >> 3;
    nt = r >> 2;
    mt = (xcd << 2) | (r & 3);
}

// ---------------------------------------------------------------------------
// prep_kernel: pure casts (memory-bound).
//   blocks 0..4095    : Wq|Wk|Wv|Wo -> Wcat bf16 [4096][1024]
//   blocks 4096..8191 : x -> xb bf16 [4096][1024]
//   blocks 8192..8223 : [Ww;We] -> WG2 bf16 rows 0..31 (gate B-tile)
// ---------------------------------------------------------------------------
__global__ __launch_bounds__(256)
void prep_kernel(const float* __restrict__ x,
                 const float* __restrict__ Wq, const float* __restrict__ Wk,
                 const float* __restrict__ Wv, const float* __restrict__ Wo,
                 const float* __restrict__ Ww, const float* __restrict__ We,
                 u16* __restrict__ Wcat, u16* __restrict__ xb,
                 u16* __restrict__ WG2) {
    int blk = blockIdx.x, t = threadIdx.x;
    if (blk < 4096) {
        int i = (blk * 256 + t) * 4;
        int sel = i >> 20;
        const float* s = sel == 0 ? Wq : sel == 1 ? Wk : sel == 2 ? Wv : Wo;
        float4 v = *(const float4*)(s + (i & 1048575));
        ushort4 o;
        o.x = f2bf(v.x); o.y = f2bf(v.y); o.z = f2bf(v.z); o.w = f2bf(v.w);
        *(ushort4*)(Wcat + i) = o;
    } else if (blk < 8192) {
        int i = ((blk - 4096) * 256 + t) * 4;
        float4 v = *(const float4*)(x + i);
        ushort4 o;
        o.x = f2bf(v.x); o.y = f2bf(v.y); o.z = f2bf(v.z); o.w = f2bf(v.w);
        *(ushort4*)(xb + i) = o;
    } else {
        int i = ((blk - 8192) * 256 + t) * 4;    // 0..32767
        const float* s = (i < 16384) ? (Ww + i) : (We + i - 16384);
        float4 v = *(const float4*)s;
        ushort4 o;
        o.x = f2bf(v.x); o.y = f2bf(v.y); o.z = f2bf(v.z); o.w = f2bf(v.w);
        *(ushort4*)(WG2 + i) = o;
    }
}

// ---------------------------------------------------------------------------
// QKV+gates GEMM: 128x128 tile, BK=64, 4 waves, 2-phase dbuf, XOR-swizzled
// LDS (T2/rule21), 2D XCD-aware tile map.
// nt<8  -> phi+bf16 to QK (Q cols); 8<=nt<16 -> phi+bf16 to QK (K) + Ktb^T;
// 16<=nt<24 -> V -> Vtb^T; nt==24 -> gate tile (B=WG2) -> LWG/GLOG (log2).
// ---------------------------------------------------------------------------
__global__ __launch_bounds__(256)
void gemm_fused(const u16* __restrict__ A, const u16* __restrict__ Bw,
                u16* __restrict__ QKo, u16* __restrict__ Ktb,
                u16* __restrict__ Vtb, const u16* __restrict__ WG2,
                const float* __restrict__ bw, const float* __restrict__ be,
                float* __restrict__ GLOG, float* __restrict__ LWG,
                int K) {
    __shared__ u16 As[2][8192];   // [128 row][64 k]
    __shared__ u16 Bs[2][8192];
    int t = threadIdx.x;
    int lane = t & 63;
    int w = t >> 6, wm = w >> 1, wn = w & 1;
    int l15 = lane & 15, l4 = lane >> 4;
    int mt, nt;
    xcd_decode((int)blockIdx.x, mt, nt);
    int m0 = mt * 128, n0 = nt * 128;
    bool gate = (nt == 24);
    const u16* Bbase = gate ? WG2 : (Bw + (size_t)n0 * K);

    f32x4 zz = {0.f, 0.f, 0.f, 0.f};
    f32x4 acc[4][4];
#pragma unroll
    for (int m = 0; m < 4; m++)
#pragma unroll
        for (int n = 0; n < 4; n++) acc[m][n] = zz;

    auto STAGE = [&](int buf, int k0) {
#pragma unroll
        for (int i = 0; i < 4; i++) {
            int c = i * 256 + t;
            int row = c >> 3;
            int ch = (c & 7) ^ (row & 7);
            async16(&As[buf][c * 8], A     + (size_t)(m0 + row) * K + k0 + ch * 8);
            async16(&Bs[buf][c * 8], Bbase + (size_t)row * K + k0 + ch * 8);
        }
    };

    STAGE(0, 0);
    __syncthreads();

    int KT = K >> 6, cur = 0;
    for (int kt = 0; kt < KT; kt++) {
        if (kt + 1 < KT) STAGE(cur ^ 1, (kt + 1) << 6);

        bf16x8 af[4][2], bfr[4][2];
#pragma unroll
        for (int ks = 0; ks < 2; ks++) {
#pragma unroll
            for (int m = 0; m < 4; m++) {
                int row = wm * 64 + m * 16 + l15;
                int ch = (l4 + 4 * ks) ^ (row & 7);
                af[m][ks] = *(const bf16x8*)&As[cur][row * 64 + ch * 8];
            }
#pragma unroll
            for (int n = 0; n < 4; n++) {
                int row = wn * 64 + n * 16 + l15;
                int ch = (l4 + 4 * ks) ^ (row & 7);
                bfr[n][ks] = *(const bf16x8*)&Bs[cur][row * 64 + ch * 8];
            }
        }
#pragma unroll
        for (int m = 0; m < 4; m++)
#pragma unroll
            for (int n = 0; n < 4; n++) {
                acc[m][n] = __builtin_amdgcn_mfma_f32_16x16x32_bf16(af[m][0], bfr[n][0], acc[m][n], 0, 0, 0);
                acc[m][n] = __builtin_amdgcn_mfma_f32_16x16x32_bf16(af[m][1], bfr[n][1], acc[m][n], 0, 0, 0);
            }

        __syncthreads();
        cur ^= 1;
    }

    if (gate) {
        // gate epilogue: only cols 0..31 of this tile are live
#pragma unroll
        for (int m = 0; m < 4; m++)
#pragma unroll
            for (int n = 0; n < 4; n++) {
                int g = wn * 64 + n * 16 + l15;
                if (g < 32) {
                    int h = g & 15;
                    int rowb = m0 + wm * 64 + m * 16 + l4 * 4;
#pragma unroll
                    for (int r = 0; r < 4; r++) {
                        int row = rowb + r;
                        size_t idx = ((size_t)((row >> 11) * 16 + h)) * 2048 + (row & 2047);
                        float val = acc[m][n][r];
                        if (g < 16) {
                            float wgv = 1.f / (1.f + __expf(-(val + bw[h])));
                            LWG[idx] = __log2f(wgv);
                        } else {
                            float egv = 1.f / (1.f + __expf(-(val + be[h])));
                            GLOG[idx] = __log2f((1.f - egv) * 0.95f + 1e-8f);
                        }
                    }
                }
            }
        return;
    }

#pragma unroll
    for (int m = 0; m < 4; m++)
#pragma unroll
        for (int n = 0; n < 4; n++) {
            int colb = n0 + wn * 64 + n * 16 + l15;
            int rowb = m0 + wm * 64 + m * 16 + l4 * 4;
            if (colb < 1024) {
#pragma unroll
                for (int r = 0; r < 4; r++) {
                    float c = acc[m][n][r];
                    c = (c > 0.f) ? (c + 1.f) : __expf(c);
                    QKo[(size_t)(rowb + r) * 2048 + colb] = f2bf(c);
                }
            } else if (colb < 2048) {
                ushort4 o;
                u16 bv[4];
#pragma unroll
                for (int r = 0; r < 4; r++) {
                    float c = acc[m][n][r];
                    c = (c > 0.f) ? (c + 1.f) : __expf(c);
                    bv[r] = f2bf(c);
                    QKo[(size_t)(rowb + r) * 2048 + colb] = bv[r];
                }
                o.x = bv[0]; o.y = bv[1]; o.z = bv[2]; o.w = bv[3];
                int kcol = colb - 1024;
                int bb = rowb >> 11;
                *(ushort4*)&Ktb[((size_t)((bb * 16 + (kcol >> 6)) * 64 + (kcol & 63))) * 2048 + (rowb & 2047)] = o;
            } else {
                int vcol = colb - 2048;
                int bb = rowb >> 11;
                ushort4 o;
                o.x = f2bf(acc[m][n][0]); o.y = f2bf(acc[m][n][1]);
                o.z = f2bf(acc[m][n][2]); o.w = f2bf(acc[m][n][3]);
                *(ushort4*)&Vtb[((size_t)((bb * 16 + (vcol >> 6)) * 64 + (vcol & 63))) * 2048 + (rowb & 2047)] = o;
            }
        }
}

// ---------------------------------------------------------------------------
// Wo GEMM: 64x128 tile, BK=64, 4 waves, 2-phase dbuf, XOR-swizzled LDS.
// 48KB LDS -> 3 blocks/CU, 512 blocks all resident.
// ---------------------------------------------------------------------------
__global__ __launch_bounds__(256)
void gemm_wo64(const u16* __restrict__ A, const u16* __restrict__ Bw,
               float* __restrict__ Cout, int MT, int N, int K) {
    __shared__ u16 As[2][4096];   // [64 row][64 k]
    __shared__ u16 Bs[2][8192];   // [128 row][64 k]
    int t = threadIdx.x;
    int id = (int)blockIdx.x;
    int lane = t & 63;
    int w = t >> 6, wm = w >> 1, wn = w & 1;
    int l15 = lane & 15, l4 = lane >> 4;
    int m0 = (id % MT) * 64, n0 = (id / MT) * 128;

    f32x4 zz = {0.f, 0.f, 0.f, 0.f};
    f32x4 acc[2][4];
#pragma unroll
    for (int m = 0; m < 2; m++)
#pragma unroll
        for (int n = 0; n < 4; n++) acc[m][n] = zz;

    auto STAGE = [&](int buf, int k0) {
#pragma unroll
        for (int i = 0; i < 2; i++) {
            int c = i * 256 + t;
            int row = c >> 3;
            int ch = (c & 7) ^ (row & 7);
            async16(&As[buf][c * 8], A + (size_t)(m0 + row) * K + k0 + ch * 8);
        }
#pragma unroll
        for (int i = 0; i < 4; i++) {
            int c = i * 256 + t;
            int row = c >> 3;
            int ch = (c & 7) ^ (row & 7);
            async16(&Bs[buf][c * 8], Bw + (size_t)(n0 + row) * K + k0 + ch * 8);
        }
    };

    STAGE(0, 0);
    __syncthreads();

    int KT = K >> 6, cur = 0;
    for (int kt = 0; kt < KT; kt++) {
        if (kt + 1 < KT) STAGE(cur ^ 1, (kt + 1) << 6);

        bf16x8 af[2][2], bfr[4][2];
#pragma unroll
        for (int ks = 0; ks < 2; ks++) {
#pragma unroll
            for (int m = 0; m < 2; m++) {
                int row = wm * 32 + m * 16 + l15;
                int ch = (l4 + 4 * ks) ^ (row & 7);
                af[m][ks] = *(const bf16x8*)&As[cur][row * 64 + ch * 8];
            }
#pragma unroll
            for (int n = 0; n < 4; n++) {
                int row = wn * 64 + n * 16 + l15;
                int ch = (l4 + 4 * ks) ^ (row & 7);
                bfr[n][ks] = *(const bf16x8*)&Bs[cur][row * 64 + ch * 8];
            }
        }
#pragma unroll
        for (int m = 0; m < 2; m++)
#pragma unroll
            for (int n = 0; n < 4; n++) {
                acc[m][n] = __builtin_amdgcn_mfma_f32_16x16x32_bf16(af[m][0], bfr[n][0], acc[m][n], 0, 0, 0);
                acc[m][n] = __builtin_amdgcn_mfma_f32_16x16x32_bf16(af[m][1], bfr[n][1], acc[m][n], 0, 0, 0);
            }

        __syncthreads();
        cur ^= 1;
    }

#pragma unroll
    for (int m = 0; m < 2; m++)
#pragma unroll
        for (int n = 0; n < 4; n++) {
            int colb = n0 + wn * 64 + n * 16 + l15;
            int rowb = m0 + wm * 32 + m * 16 + l4 * 4;
#pragma unroll
            for (int r = 0; r < 4; r++)
                Cout[(size_t)(rowb + r) * N + colb] = acc[m][n][r];
        }
}

// ---------------------------------------------------------------------------
// Phase A: per-chunk state delta. Block = (chunk c, bh), 128 thr = 2 waves.
// Scan-free: wave 0 computes the chunk-local prefix sum of GLOG in-kernel.
// exponent(j) = cref - cjl[j] where cref = pfx_63, cjl[j] = pfx_j - LWG_j
//            = sum_{l>j} GLOG_l + LWG_j  (identical to old CC/CJW form).
// ---------------------------------------------------------------------------
__global__ __launch_bounds__(128)
void state_delta(const u16* __restrict__ Ktb, const u16* __restrict__ Vtb,
                 const float* __restrict__ GLOG, const float* __restrict__ LWG,
                 u16* __restrict__ dSg, float* __restrict__ dZg) {
    __shared__ u16 Kts[4096], Vts[4096];
    __shared__ float cjl[64];
    __shared__ float creff;
    int c = blockIdx.x, bh = blockIdx.y;
    int j0 = c * 64;
    int t = threadIdx.x, w = t >> 6, lane = t & 63, l31 = lane & 31, hi = lane >> 5;
    const u16* ktg = Ktb + (size_t)(bh * 64) * 2048 + j0;
    const u16* vtg = Vtb + (size_t)(bh * 64) * 2048 + j0;
#pragma unroll
    for (int rnd = 0; rnd < 4; rnd++) {
        int cc_ = rnd * 128 + t; int row = cc_ >> 3; int ch = (cc_ & 7) ^ (row & 7);
        async16(&Kts[cc_ * 8], ktg + (size_t)row * 2048 + ch * 8);
        async16(&Vts[cc_ * 8], vtg + (size_t)row * 2048 + ch * 8);
    }
    if (t < 64) {
        float v = GLOG[(size_t)bh * L_ + j0 + t];
        float lw = LWG[(size_t)bh * L_ + j0 + t];
#pragma unroll
        for (int off = 1; off < 64; off <<= 1) {
            float u = __shfl_up(v, off, 64);
            if (t >= off) v += u;
        }
        cjl[t] = v - lw;
        if (t == 63) creff = v;
    }
    __syncthreads();
    float cref = creff;

    f32x16 zz16;
#pragma unroll
    for (int r = 0; r < 16; r++) zz16[r] = 0.f;
    int swz = l31 & 7;
    int vq = w;
    u16* base = dSg + (size_t)(bh * 32 + c) * 4096;

#pragma unroll
    for (int kq = 0; kq < 2; kq++) {
        f32x16 acc = zz16;
        float zs = 0.f;
#pragma unroll
        for (int ks = 0; ks < 4; ks++) {
            int ch = (ks * 2 + hi) ^ swz;
            bf16x8 kt = *(const bf16x8*)&Kts[(kq * 32 + l31) * 64 + ch * 8];
            bf16x8 vt = *(const bf16x8*)&Vts[(vq * 32 + l31) * 64 + ch * 8];
            union { unsigned u[4]; bf16x8 v; } kw;
#pragma unroll
            for (int e2 = 0; e2 < 4; e2++) {
                int jb = ks * 16 + hi * 8 + e2 * 2;
                float f0 = bf2f(kt[e2 * 2 + 0]) * fexp2(cref - cjl[jb]);
                float f1 = bf2f(kt[e2 * 2 + 1]) * fexp2(cref - cjl[jb + 1]);
                zs += f0 + f1;
                asm("v_cvt_pk_bf16_f32 %0, %1, %2" : "=v"(kw.u[e2]) : "v"(f0), "v"(f1));
            }
            acc = __builtin_amdgcn_mfma_f32_32x32x16_bf16(vt, kw.v, acc, 0, 0, 0);
        }
#pragma unroll
        for (int r = 0; r < 16; r++) {
            int v = vq * 32 + (r & 3) + 8 * (r >> 2) + 4 * hi;
            base[v * 64 + kq * 32 + l31] = f2bf(acc[r]);
        }
        if (w == 0) {
            zs += __shfl_xor(zs, 32, 64);
            if (hi == 0)
                dZg[(size_t)(bh * 32 + c) * 64 + kq * 32 + l31] = zs;
        }
    }
}

// ---------------------------------------------------------------------------
// Phase B: per-element scan over 32 chunks. lam[c] = 2^(chunk-sum of GLOG),
// computed in-kernel (8 lanes per chunk, shfl_xor reduce) -- no global scan.
// ---------------------------------------------------------------------------
__global__ __launch_bounds__(256)
void state_scan(const u16* __restrict__ dSg, const float* __restrict__ dZg,
                const float* __restrict__ GLOG,
                u16* __restrict__ Sg, float* __restrict__ Zg) {
    __shared__ float lam[32];
    int bh = blockIdx.x, slice = blockIdx.y;
    int t = threadIdx.x;
    {
        int cc8 = t >> 3, p8 = t & 7;
        const float* gl = GLOG + (size_t)bh * L_ + cc8 * 64 + p8 * 8;
        float s = 0.f;
#pragma unroll
        for (int e = 0; e < 8; e++) s += gl[e];
        s += __shfl_xor(s, 1, 64);
        s += __shfl_xor(s, 2, 64);
        s += __shfl_xor(s, 4, 64);
        if (p8 == 0) lam[cc8] = cc8 ? fexp2(s) : 0.f;
    }
    __syncthreads();
    if (slice < 8) {
        int eidx = slice * 512 + t * 2;
        float s0 = 0.f, s1 = 0.f;
#pragma unroll 8
        for (int c = 0; c < 32; c++) {
            unsigned d = *(const unsigned*)&dSg[(size_t)(bh * 32 + c) * 4096 + eidx];
            float l = lam[c];
            s0 = l * s0 + bf2f((short)(d & 0xffff));
            s1 = l * s1 + bf2f((short)(d >> 16));
            unsigned o;
            asm("v_cvt_pk_bf16_f32 %0, %1, %2" : "=v"(o) : "v"(s0), "v"(s1));
            *(unsigned*)&Sg[(size_t)(bh * 32 + c) * 4096 + eidx] = o;
        }
    } else if (t < 64) {
        float z = 0.f;
#pragma unroll 8
        for (int c = 0; c < 32; c++) {
            z = lam[c] * z + dZg[(size_t)(bh * 32 + c) * 64 + t];
            Zg[(size_t)(bh * 32 + c) * 64 + t] = z;
        }
    }
}

// ---------------------------------------------------------------------------
// Phase C: output. Scan-free: wave 0 computes local prefix pfx of GLOG;
// ccl[i] = pfx_i (so 2^(ccl) = inter-scale), cjl[j] = pfx_j - LWG_j.
// Downstream math identical to the old CC/CJW form with cpv == 0.
// ---------------------------------------------------------------------------
__global__ __launch_bounds__(128)
void attn_out(const u16* __restrict__ QK, const u16* __restrict__ Vtb,
              const u16* __restrict__ Sg, const float* __restrict__ Zg,
              const float* __restrict__ GLOG, const float* __restrict__ LWG,
              u16* __restrict__ AOb) {
    __shared__ u16 Qs[4096], Ks[4096], Vts[4096], Ss[4096];
    __shared__ float ccl[64], cjl[64], zbl[64];
    int c = blockIdx.x, bh = blockIdx.y;
    int b = bh >> 4, h = bh & 15;
    int j0 = c * 64;
    int t = threadIdx.x, w = t >> 6, lane = t & 63, l31 = lane & 31, hi = lane >> 5;
    int w32 = w * 32;

    const u16* qkg = QK + (size_t)(b * L_ + j0) * 2048 + h * 64;
    const u16* vtg = Vtb + (size_t)(bh * 64) * 2048 + j0;
#pragma unroll
    for (int rnd = 0; rnd < 4; rnd++) {
        int cc_ = rnd * 128 + t; int row = cc_ >> 3; int ch = (cc_ & 7) ^ (row & 7);
        async16(&Qs[cc_ * 8],  qkg + (size_t)row * 2048 + ch * 8);
        async16(&Ks[cc_ * 8],  qkg + (size_t)row * 2048 + 1024 + ch * 8);
        async16(&Vts[cc_ * 8], vtg + (size_t)row * 2048 + ch * 8);
    }
    if (c) {
        const u16* sg = Sg + (size_t)(bh * 32 + c - 1) * 4096;
#pragma unroll
        for (int rnd = 0; rnd < 4; rnd++) {
            int cc_ = rnd * 128 + t; int row = cc_ >> 3; int ch = (cc_ & 7) ^ (row & 7);
            async16(&Ss[cc_ * 8], sg + row * 64 + ch * 8);
        }
        if (t < 64) zbl[t] = Zg[(size_t)(bh * 32 + c - 1) * 64 + t];  // plain store
    }
    // wave-0 local prefix scan (rule 21: plain stores, no async16 here)
    if (t < 64) {
        float v = GLOG[(size_t)bh * L_ + j0 + t];
        float lw = LWG[(size_t)bh * L_ + j0 + t];
#pragma unroll
        for (int off = 1; off < 64; off <<= 1) {
            float u = __shfl_up(v, off, 64);
            if (t >= off) v += u;
        }
        ccl[t] = v;
        cjl[t] = v - lw;
    }
    __syncthreads();

    f32x16 zz16;
#pragma unroll
    for (int r = 0; r < 16; r++) zz16[r] = 0.f;
    int swz = l31 & 7;

    // Q fragments (A- and B-operand layouts are identical: lane&31 = row)
    bf16x8 qb[4];
#pragma unroll
    for (int ks = 0; ks < 4; ks++) {
        int ch = (ks * 2 + hi) ^ swz;
        qb[ks] = *(const bf16x8*)&Qs[(w32 + l31) * 64 + ch * 8];
    }
    float ci = ccl[w32 + l31];

    // ---- intra QK^T (swapped): st = S^T frag, i = l31 col ----
    f32x16 st[2];
    st[0] = zz16; st[1] = zz16;
    __builtin_amdgcn_s_setprio(1);
#pragma unroll
    for (int ks = 0; ks < 4; ks++) {
        int ch = (ks * 2 + hi) ^ swz;
        bf16x8 k0 = *(const bf16x8*)&Ks[l31 * 64 + ch * 8];
        bf16x8 k1 = *(const bf16x8*)&Ks[(32 + l31) * 64 + ch * 8];
        st[0] = __builtin_amdgcn_mfma_f32_32x32x16_bf16(k0, qb[ks], st[0], 0, 0, 0);
        st[1] = __builtin_amdgcn_mfma_f32_32x32x16_bf16(k1, qb[ks], st[1], 0, 0, 0);
    }
    __builtin_amdgcn_s_setprio(0);

    // ---- P build (triangular), pack bf16 ----
    unsigned pk[2][4][2];
    float dloc = 0.f;
    int lim = w32 + l31;
#pragma unroll
    for (int n = 0; n < 2; n++) {
#pragma unroll
        for (int rq = 0; rq < 4; rq++) {
            float4 cj4 = *(const float4*)&cjl[n * 32 + rq * 8 + hi * 4];
            float e0 = st[n][rq * 4 + 0] * fexp2(ci - cj4.x);
            float e1 = st[n][rq * 4 + 1] * fexp2(ci - cj4.y);
            float e2 = st[n][rq * 4 + 2] * fexp2(ci - cj4.z);
            float e3 = st[n][rq * 4 + 3] * fexp2(ci - cj4.w);
            int jb = n * 32 + rq * 8 + hi * 4;
            e0 = (jb + 0 <= lim) ? e0 : 0.f;
            e1 = (jb + 1 <= lim) ? e1 : 0.f;
            e2 = (jb + 2 <= lim) ? e2 : 0.f;
            e3 = (jb + 3 <= lim) ? e3 : 0.f;
            dloc += (e0 + e1) + (e2 + e3);
            asm("v_cvt_pk_bf16_f32 %0, %1, %2" : "=v"(pk[n][rq][0]) : "v"(e0), "v"(e1));
            asm("v_cvt_pk_bf16_f32 %0, %1, %2" : "=v"(pk[n][rq][1]) : "v"(e2), "v"(e3));
        }
    }

    // ---- PV ----
    f32x16 acc0 = zz16, acc1 = zz16;
    __builtin_amdgcn_s_setprio(1);
#pragma unroll
    for (int wi = 0; wi < 4; wi++) {
        int n = wi >> 1, qA = 2 * (wi & 1), qB = qA + 1;
        unsigned a0 = pk[n][qA][0], b0 = pk[n][qB][0];
        unsigned a1 = pk[n][qA][1], b1 = pk[n][qB][1];
        asm volatile("v_permlane32_swap_b32 %0, %1" : "+v"(a0), "+v"(b0));
        asm volatile("v_permlane32_swap_b32 %0, %1" : "+v"(a1), "+v"(b1));
        union { unsigned u[4]; bf16x8 v; } aw;
        aw.u[0] = a0; aw.u[1] = a1; aw.u[2] = b0; aw.u[3] = b1;
        int jc = (wi * 2 + hi) ^ swz;
        bf16x8 v0 = *(const bf16x8*)&Vts[l31 * 64 + jc * 8];
        bf16x8 v1 = *(const bf16x8*)&Vts[(32 + l31) * 64 + jc * 8];
        acc0 = __builtin_amdgcn_mfma_f32_32x32x16_bf16(aw.v, v0, acc0, 0, 0, 0);
        acc1 = __builtin_amdgcn_mfma_f32_32x32x16_bf16(aw.v, v1, acc1, 0, 0, 0);
    }
    __builtin_amdgcn_s_setprio(0);

    // ---- inter: Q @ S_{c-1}, Q . z_{c-1} ----
    if (c) {
        f32x16 oi0 = zz16, oi1 = zz16;
        __builtin_amdgcn_s_setprio(1);
#pragma unroll
        for (int ks = 0; ks < 4; ks++) {
            int ch = (ks * 2 + hi) ^ swz;
            bf16x8 s0 = *(const bf16x8*)&Ss[l31 * 64 + ch * 8];
            bf16x8 s1 = *(const bf16x8*)&Ss[(32 + l31) * 64 + ch * 8];
            oi0 = __builtin_amdgcn_mfma_f32_32x32x16_bf16(qb[ks], s0, oi0, 0, 0, 0);
            oi1 = __builtin_amdgcn_mfma_f32_32x32x16_bf16(qb[ks], s1, oi1, 0, 0, 0);
        }
        __builtin_amdgcn_s_setprio(0);
#pragma unroll
        for (int r = 0; r < 16; r++) {
            int il = (r & 3) + 8 * (r >> 2) + 4 * hi;
            float sc = fexp2(ccl[w32 + il]);
            acc0[r] += sc * oi0[r];
            acc1[r] += sc * oi1[r];
        }
        float dq = 0.f;
#pragma unroll
        for (int ks = 0; ks < 4; ks++)
#pragma unroll
            for (int e = 0; e < 8; e++)
                dq += bf2f(qb[ks][e]) * zbl[ks * 16 + hi * 8 + e];
        dloc += fexp2(ci) * dq;
    }

    // ---- denominator broadcast + output ----
    float dl = dloc + __shfl_xor(dloc, 32, 64);
#pragma unroll
    for (int r = 0; r < 16; r++) {
        int il = (r & 3) + 8 * (r >> 2) + 4 * hi;
        float dv = __shfl(dl, il, 64);
        float inv = 1.f / (dv + 1e-6f);
        int ig = j0 + w32 + il;
        AOb[(size_t)(b * L_ + ig) * D_ + h * DH + l31]      = f2bf(acc0[r] * inv);
        AOb[(size_t)(b * L_ + ig) * D_ + h * DH + 32 + l31] = f2bf(acc1[r] * inv);
    }
}

// ---------------------------------------------------------------------------
extern "C" void kernel_launch(void* const* d_in, const int* in_sizes, int n_in,
                              void* d_out, int out_size, void* d_ws, size_t ws_size,
                              hipStream_t stream) {
    const float* x  = (const float*)d_in[0];
    const float* Wq = (const float*)d_in[1];
    const float* Wk = (const float*)d_in[2];
    const float* Wv = (const float*)d_in[3];
    const float* Wo = (const float*)d_in[4];
    const float* Ww = (const float*)d_in[5];
    const float* bw = (const float*)d_in[6];
    const float* We = (const float*)d_in[7];
    const float* be = (const float*)d_in[8];
    float* out = (float*)d_out;

    char* wsb = (char*)d_ws;
    u16* xb   = (u16*)(wsb);                        // 8MB (dead after QKV gemm)
    u16* Sg   = xb;                                 // 8MB, reuses xb region
    u16* Wcat = (u16*)(wsb + ((size_t)8  << 20));   // 8MB  [Wq;Wk;Wv;Wo] bf16
    u16* QK   = (u16*)(wsb + ((size_t)16 << 20));   // 16MB [4096][2048] Q|K phi'd
    u16* Vtb  = (u16*)(wsb + ((size_t)32 << 20));   // 8MB  [B*H*64][2048]
    u16* Ktb  = (u16*)(wsb + ((size_t)40 << 20));   // 8MB  [B*H*64][2048]
    u16* AOb  = (u16*)(wsb + ((size_t)48 << 20));   // 8MB  [4096][1024]
    u16* dSg  = AOb;                                // 8MB, consumed before AOb written
    float* GLOG = (float*)(wsb + ((size_t)56 << 20));
    float* LWG  = GLOG + 65536;
    float* dZg  = LWG  + 65536;   // 256KB
    float* Zg   = dZg  + 65536;   // 256KB
    u16*  WG2  = (u16*)(Zg + 65536);   // 256KB [128][1024] bf16 gate B-tile

    // 1) pure casts: weights, x, gate-weights
    prep_kernel<<<8224, 256, 0, stream>>>(
        x, Wq, Wk, Wv, Wo, Ww, We, Wcat, xb, WG2);

    // 2) fused QKV + gates projection (32 m x 25 n, 2D-XCD mapped)
    gemm_fused<<<32 * 25, 256, 0, stream>>>(
        xb, Wcat, QK, Ktb, Vtb, WG2, bw, be, GLOG, LWG, D_);

    // 3-5) chunked linear attention (scan-free: local prefix sums in-kernel)
    state_delta<<<dim3(32, B_ * H_), 128, 0, stream>>>(Ktb, Vtb, GLOG, LWG, dSg, dZg);
    state_scan<<<dim3(B_ * H_, 9), 256, 0, stream>>>(dSg, dZg, GLOG, Sg, Zg);
    attn_out<<<dim3(32, B_ * H_), 128, 0, stream>>>(QK, Vtb, Sg, Zg, GLOG, LWG, AOb);

    // 6) output projection: 64x128 tiles, 512 blocks, 3 blocks/CU
    gemm_wo64<<<(ML / 64) * (D_ / 128), 256, 0, stream>>>(
        AOb, Wcat + (size_t)3072 * 1024, out, ML / 64, D_, D_);
}